// Round 1
// baseline (1922.949 us; speedup 1.0000x reference)
//
#include <hip/hip_runtime.h>
#include <hip/hip_bf16.h>

#define NN 50000
#define NE 800000
#define FIN 128
#define HCC 256   // HEADS*HID
#define OC 64
#define NSL 0.2f

// ---------------- CSR build ----------------
__global__ void k_hist(const int* __restrict__ dst, int* __restrict__ deg, int n) {
  int i = blockIdx.x * blockDim.x + threadIdx.x;
  int st = gridDim.x * blockDim.x;
  for (; i < n; i += st) atomicAdd(&deg[dst[i]], 1);
}

__global__ __launch_bounds__(1024) void k_scan(const int* __restrict__ deg,
                                               int* __restrict__ row_ptr,
                                               int* __restrict__ cursor, int n) {
  __shared__ int sums[1024];
  int t = threadIdx.x;
  int chunk = (n + 1023) >> 10;
  int lo = t * chunk;
  int hi = min(lo + chunk, n);
  int s = 0;
  for (int i = lo; i < hi; ++i) s += deg[i];
  sums[t] = s;
  __syncthreads();
  for (int off = 1; off < 1024; off <<= 1) {
    int v = (t >= off) ? sums[t - off] : 0;
    __syncthreads();
    sums[t] += v;
    __syncthreads();
  }
  int base = (t == 0) ? 0 : sums[t - 1];
  for (int i = lo; i < hi; ++i) {
    row_ptr[i] = base;
    cursor[i] = base;
    base += deg[i];
  }
  if (t == 1023) row_ptr[n] = sums[1023];
}

__global__ void k_scatter(const int* __restrict__ srcv, const int* __restrict__ dstv,
                          int* __restrict__ cursor, int* __restrict__ csr_src, int n) {
  int i = blockIdx.x * blockDim.x + threadIdx.x;
  int st = gridDim.x * blockDim.x;
  for (; i < n; i += st) {
    int pos = atomicAdd(&cursor[dstv[i]], 1);
    csr_src[pos] = srcv[i];
  }
}

// ---------------- fp32 GEMM: C[M,N] = A[M,K] @ B[K,N], optional relu on A ----------------
// 128x64 tile, BK=32, 256 threads, each thread 8x4 outputs.
template<bool RELU_A>
__global__ __launch_bounds__(256) void k_gemm(const float* __restrict__ A,
                                              const float* __restrict__ B,
                                              float* __restrict__ C,
                                              int M, int N, int K) {
  __shared__ float As[32][132];  // [k][m], padded
  __shared__ float Bs[32][64];   // [k][n]
  const int tid = threadIdx.x;
  const int bm = blockIdx.y * 128;
  const int bn = blockIdx.x * 64;
  const int tc = tid & 15;   // col group: 4 cols
  const int tr = tid >> 4;   // row group: 8 rows
  float acc[8][4] = {};

  for (int kt = 0; kt < K; kt += 32) {
    // A tile 128x32: 1024 float4, 4 per thread
#pragma unroll
    for (int l = 0; l < 4; ++l) {
      int f = l * 256 + tid;
      int row = f >> 3;        // 0..127
      int c4 = f & 7;          // 0..7
      int gr = bm + row;
      float4 v = make_float4(0.f, 0.f, 0.f, 0.f);
      if (gr < M) v = *(const float4*)&A[(size_t)gr * K + kt + c4 * 4];
      if (RELU_A) {
        v.x = fmaxf(v.x, 0.f); v.y = fmaxf(v.y, 0.f);
        v.z = fmaxf(v.z, 0.f); v.w = fmaxf(v.w, 0.f);
      }
      As[c4 * 4 + 0][row] = v.x;
      As[c4 * 4 + 1][row] = v.y;
      As[c4 * 4 + 2][row] = v.z;
      As[c4 * 4 + 3][row] = v.w;
    }
    // B tile 32x64: 512 float4, 2 per thread
#pragma unroll
    for (int l = 0; l < 2; ++l) {
      int f = l * 256 + tid;
      int row = f >> 4;        // 0..31
      int c4 = f & 15;         // 0..15
      *(float4*)&Bs[row][c4 * 4] = *(const float4*)&B[(size_t)(kt + row) * N + bn + c4 * 4];
    }
    __syncthreads();
#pragma unroll
    for (int kk = 0; kk < 32; ++kk) {
      float4 a0 = *(const float4*)&As[kk][tr * 8];
      float4 a1 = *(const float4*)&As[kk][tr * 8 + 4];
      float4 bv = *(const float4*)&Bs[kk][tc * 4];
      float a[8] = {a0.x, a0.y, a0.z, a0.w, a1.x, a1.y, a1.z, a1.w};
      float b[4] = {bv.x, bv.y, bv.z, bv.w};
#pragma unroll
      for (int i = 0; i < 8; ++i)
#pragma unroll
        for (int j = 0; j < 4; ++j)
          acc[i][j] = fmaf(a[i], b[j], acc[i][j]);
    }
    __syncthreads();
  }
#pragma unroll
  for (int i = 0; i < 8; ++i) {
    int r = bm + tr * 8 + i;
    if (r < M) {
      float4 v = make_float4(acc[i][0], acc[i][1], acc[i][2], acc[i][3]);
      *(float4*)&C[(size_t)r * N + bn + tc * 4] = v;
    }
  }
}

// ---------------- attention coefficients: al_s[n,h], al_d[n,h] ----------------
__global__ __launch_bounds__(256) void k_alpha(const float* __restrict__ h,
                                               const float* __restrict__ a_s,
                                               const float* __restrict__ a_d,
                                               float* __restrict__ als,
                                               float* __restrict__ ald) {
  int gid = blockIdx.x * blockDim.x + threadIdx.x;
  int n = gid >> 6;
  int lane = threadIdx.x & 63;
  if (n >= NN) return;
  float4 hv = *(const float4*)&h[(size_t)n * HCC + lane * 4];
  float4 s4 = *(const float4*)&a_s[lane * 4];
  float4 d4 = *(const float4*)&a_d[lane * 4];
  float ss = hv.x * s4.x + hv.y * s4.y + hv.z * s4.z + hv.w * s4.w;
  float sd = hv.x * d4.x + hv.y * d4.y + hv.z * d4.z + hv.w * d4.w;
#pragma unroll
  for (int m = 1; m < 16; m <<= 1) {
    ss += __shfl_xor(ss, m);
    sd += __shfl_xor(sd, m);
  }
  if ((lane & 15) == 0) {
    int head = lane >> 4;
    als[n * 4 + head] = ss;
    ald[n * 4 + head] = sd;
  }
}

// ---------------- CSR gather: one wave per dst node ----------------
// lane i handles channels [4i,4i+4); head = i/16.  wsum = softmax denom (no max
// subtraction needed: logits are O(1)).  out += acc/wsum + bias (CONCAT) or
// head-mean (non-concat).
template<bool CONCAT, bool SELFLOOP>
__global__ __launch_bounds__(256) void k_gather(const float* __restrict__ h,
                                                const float* __restrict__ als,
                                                const float* __restrict__ ald,
                                                const int* __restrict__ row_ptr,
                                                const int* __restrict__ csr_src,
                                                const float* __restrict__ bias,
                                                float* __restrict__ outp) {
  int gid = blockIdx.x * blockDim.x + threadIdx.x;
  int n = gid >> 6;
  int lane = threadIdx.x & 63;
  if (n >= NN) return;
  int head = lane >> 4;
  float ad = ald[n * 4 + head];
  int rs = row_ptr[n];
  int re = row_ptr[n + 1];
  float ax = 0.f, ay = 0.f, az = 0.f, aw = 0.f;
  float wsum = 0.f;
  for (int i = rs; i < re; ++i) {
    int s = csr_src[i];
    float lg = als[s * 4 + head] + ad;
    lg = (lg > 0.f) ? lg : NSL * lg;
    float w = __expf(lg);
    wsum += w;
    float4 hv = *(const float4*)&h[(size_t)s * HCC + lane * 4];
    ax = fmaf(w, hv.x, ax);
    ay = fmaf(w, hv.y, ay);
    az = fmaf(w, hv.z, az);
    aw = fmaf(w, hv.w, aw);
  }
  if (SELFLOOP) {
    float lg = als[n * 4 + head] + ad;
    lg = (lg > 0.f) ? lg : NSL * lg;
    float w = __expf(lg);
    wsum += w;
    float4 hv = *(const float4*)&h[(size_t)n * HCC + lane * 4];
    ax = fmaf(w, hv.x, ax);
    ay = fmaf(w, hv.y, ay);
    az = fmaf(w, hv.z, az);
    aw = fmaf(w, hv.w, aw);
  }
  float inv = 1.0f / (wsum + 1e-16f);
  if (CONCAT) {
    size_t base = (size_t)n * HCC + lane * 4;
    float4 o = *(float4*)&outp[base];
    float4 bb = *(const float4*)&bias[lane * 4];
    o.x += ax * inv + bb.x;
    o.y += ay * inv + bb.y;
    o.z += az * inv + bb.z;
    o.w += aw * inv + bb.w;
    *(float4*)&outp[base] = o;
  } else {
    float vx = ax * inv, vy = ay * inv, vz = az * inv, vw = aw * inv;
    vx += __shfl_xor(vx, 16); vy += __shfl_xor(vy, 16);
    vz += __shfl_xor(vz, 16); vw += __shfl_xor(vw, 16);
    vx += __shfl_xor(vx, 32); vy += __shfl_xor(vy, 32);
    vz += __shfl_xor(vz, 32); vw += __shfl_xor(vw, 32);
    if (lane < 16) {
      size_t base = (size_t)n * OC + lane * 4;
      float4 o = *(float4*)&outp[base];
      float4 bb = *(const float4*)&bias[lane * 4];
      o.x += 0.25f * vx + bb.x;
      o.y += 0.25f * vy + bb.y;
      o.z += 0.25f * vz + bb.z;
      o.w += 0.25f * vw + bb.w;
      *(float4*)&outp[base] = o;
    }
  }
}

// ---------------- final: out = relu(out2) @ Wl + bl ----------------
__global__ __launch_bounds__(256) void k_final(const float* __restrict__ out2,
                                               const float* __restrict__ Wl,
                                               const float* __restrict__ bl,
                                               float* __restrict__ outp) {
  __shared__ float Ws[64 * 64];
  __shared__ float bs[64];
  int tid = threadIdx.x;
  for (int i = tid; i < 4096; i += 256) Ws[i] = Wl[i];
  if (tid < 64) bs[tid] = bl[tid];
  __syncthreads();
  int r = blockIdx.x * 4 + (tid >> 6);
  int c = tid & 63;
  if (r >= NN) return;
  const float* xr = &out2[(size_t)r * OC];
  float acc = bs[c];
#pragma unroll
  for (int k = 0; k < 64; ++k) {
    float xv = xr[k];
    xv = (xv > 0.f) ? xv : 0.f;
    acc = fmaf(xv, Ws[k * 64 + c], acc);
  }
  outp[(size_t)r * OC + c] = acc;
}

extern "C" void kernel_launch(void* const* d_in, const int* in_sizes, int n_in,
                              void* d_out, int out_size, void* d_ws, size_t ws_size,
                              hipStream_t stream) {
  const float* x   = (const float*)d_in[0];
  const int* e_b   = (const int*)d_in[1];
  const int* e_sp  = (const int*)d_in[2];
  const int* e_si  = (const int*)d_in[3];
  const float* W1  = (const float*)d_in[4];
  const float* a1s = (const float*)d_in[5];
  const float* a1d = (const float*)d_in[6];
  const float* b1  = (const float*)d_in[7];
  const float* W2  = (const float*)d_in[8];
  const float* a2s = (const float*)d_in[9];
  const float* a2d = (const float*)d_in[10];
  const float* b2  = (const float*)d_in[11];
  const float* Wl  = (const float*)d_in[12];
  const float* bl  = (const float*)d_in[13];
  float* out = (float*)d_out;

  char* ws = (char*)d_ws;
  size_t off = 0;
  auto alloc = [&](size_t b) {
    char* p = ws + off;
    off += (b + 255) & ~(size_t)255;
    return p;
  };
  float* h    = (float*)alloc((size_t)NN * HCC * 4);
  float* out1 = (float*)alloc((size_t)NN * HCC * 4);
  float* out2 = (float*)alloc((size_t)NN * OC * 4);
  float* als  = (float*)alloc((size_t)NN * 4 * 4);
  float* ald  = (float*)alloc((size_t)NN * 4 * 4);
  int* deg    = (int*)alloc((size_t)NN * 4);
  int* cursor = (int*)alloc((size_t)(NN + 1) * 4);
  int* rp[3];
  int* cs[3];
  for (int r = 0; r < 3; ++r) {
    rp[r] = (int*)alloc((size_t)(NN + 1) * 4);
    cs[r] = (int*)alloc((size_t)NE * 4);
  }

  const int* edges[3] = {e_b, e_sp, e_si};

  // CSR build (shared by both layers)
  for (int r = 0; r < 3; ++r) {
    hipMemsetAsync(deg, 0, (size_t)NN * 4, stream);
    k_hist<<<1024, 256, 0, stream>>>(edges[r] + NE, deg, NE);
    k_scan<<<1, 1024, 0, stream>>>(deg, rp[r], cursor, NN);
    k_scatter<<<1024, 256, 0, stream>>>(edges[r], edges[r] + NE, cursor, cs[r], NE);
  }
  hipMemsetAsync(out1, 0, (size_t)NN * HCC * 4, stream);
  hipMemsetAsync(out2, 0, (size_t)NN * OC * 4, stream);

  dim3 ggrid(HCC / 64, (NN + 127) / 128);
  const int ablocks = (NN * 64) / 256;  // 12500

  // layer 1 (concat)
  for (int r = 0; r < 3; ++r) {
    k_gemm<false><<<ggrid, 256, 0, stream>>>(x, W1 + (size_t)r * FIN * HCC, h, NN, HCC, FIN);
    k_alpha<<<ablocks, 256, 0, stream>>>(h, a1s + r * HCC, a1d + r * HCC, als, ald);
    if (r == 0)
      k_gather<true, false><<<ablocks, 256, 0, stream>>>(h, als, ald, rp[r], cs[r], b1 + r * HCC, out1);
    else
      k_gather<true, true><<<ablocks, 256, 0, stream>>>(h, als, ald, rp[r], cs[r], b1 + r * HCC, out1);
  }
  // layer 2 (mean over heads); relu on layer-1 output fused into GEMM A-load
  for (int r = 0; r < 3; ++r) {
    k_gemm<true><<<ggrid, 256, 0, stream>>>(out1, W2 + (size_t)r * HCC * HCC, h, NN, HCC, HCC);
    k_alpha<<<ablocks, 256, 0, stream>>>(h, a2s + r * HCC, a2d + r * HCC, als, ald);
    if (r == 0)
      k_gather<false, false><<<ablocks, 256, 0, stream>>>(h, als, ald, rp[r], cs[r], b2 + r * OC, out2);
    else
      k_gather<false, true><<<ablocks, 256, 0, stream>>>(h, als, ald, rp[r], cs[r], b2 + r * OC, out2);
  }
  // final linear (relu on out2 fused)
  k_final<<<(NN + 3) / 4, 256, 0, stream>>>(out2, Wl, bl, out);
}

// Round 2
// 1737.010 us; speedup vs baseline: 1.1070x; 1.1070x over previous
//
#include <hip/hip_runtime.h>
#include <hip/hip_bf16.h>
#include <hip/hip_fp16.h>

#define NN 50000
#define NE 800000
#define FIN 128
#define HCC 256   // HEADS*HID
#define OC 64
#define NSL 0.2f

struct __attribute__((aligned(8))) h4 { __half x, y, z, w; };

// ---------------- CSR build ----------------
__global__ void k_hist(const int* __restrict__ dst, int* __restrict__ deg, int n) {
  int i = blockIdx.x * blockDim.x + threadIdx.x;
  int st = gridDim.x * blockDim.x;
  for (; i < n; i += st) atomicAdd(&deg[dst[i]], 1);
}

__global__ __launch_bounds__(1024) void k_scan(const int* __restrict__ deg,
                                               int* __restrict__ row_ptr,
                                               int* __restrict__ cursor, int n) {
  __shared__ int sums[1024];
  int t = threadIdx.x;
  int chunk = (n + 1023) >> 10;
  int lo = t * chunk;
  int hi = min(lo + chunk, n);
  int s = 0;
  for (int i = lo; i < hi; ++i) s += deg[i];
  sums[t] = s;
  __syncthreads();
  for (int off = 1; off < 1024; off <<= 1) {
    int v = (t >= off) ? sums[t - off] : 0;
    __syncthreads();
    sums[t] += v;
    __syncthreads();
  }
  int base = (t == 0) ? 0 : sums[t - 1];
  for (int i = lo; i < hi; ++i) {
    row_ptr[i] = base;
    cursor[i] = base;
    base += deg[i];
  }
  if (t == 1023) row_ptr[n] = sums[1023];
}

__global__ void k_scatter(const int* __restrict__ srcv, const int* __restrict__ dstv,
                          int* __restrict__ cursor, int* __restrict__ csr_src, int n) {
  int i = blockIdx.x * blockDim.x + threadIdx.x;
  int st = gridDim.x * blockDim.x;
  for (; i < n; i += st) {
    int pos = atomicAdd(&cursor[dstv[i]], 1);
    csr_src[pos] = srcv[i];
  }
}

// ---------------- fp32 GEMM -> fp16 C: C[M,N] = A[M,K] @ B[K,N], optional relu on A ----
// 128x64 tile, BK=32, 256 threads, each thread 8x4 outputs.
template<bool RELU_A>
__global__ __launch_bounds__(256) void k_gemm(const float* __restrict__ A,
                                              const float* __restrict__ B,
                                              __half* __restrict__ C,
                                              int M, int N, int K) {
  __shared__ float As[32][132];  // [k][m], padded
  __shared__ float Bs[32][64];   // [k][n]
  const int tid = threadIdx.x;
  const int bm = blockIdx.y * 128;
  const int bn = blockIdx.x * 64;
  const int tc = tid & 15;   // col group: 4 cols
  const int tr = tid >> 4;   // row group: 8 rows
  float acc[8][4] = {};

  for (int kt = 0; kt < K; kt += 32) {
#pragma unroll
    for (int l = 0; l < 4; ++l) {
      int f = l * 256 + tid;
      int row = f >> 3;
      int c4 = f & 7;
      int gr = bm + row;
      float4 v = make_float4(0.f, 0.f, 0.f, 0.f);
      if (gr < M) v = *(const float4*)&A[(size_t)gr * K + kt + c4 * 4];
      if (RELU_A) {
        v.x = fmaxf(v.x, 0.f); v.y = fmaxf(v.y, 0.f);
        v.z = fmaxf(v.z, 0.f); v.w = fmaxf(v.w, 0.f);
      }
      As[c4 * 4 + 0][row] = v.x;
      As[c4 * 4 + 1][row] = v.y;
      As[c4 * 4 + 2][row] = v.z;
      As[c4 * 4 + 3][row] = v.w;
    }
#pragma unroll
    for (int l = 0; l < 2; ++l) {
      int f = l * 256 + tid;
      int row = f >> 4;
      int c4 = f & 15;
      *(float4*)&Bs[row][c4 * 4] = *(const float4*)&B[(size_t)(kt + row) * N + bn + c4 * 4];
    }
    __syncthreads();
#pragma unroll
    for (int kk = 0; kk < 32; ++kk) {
      float4 a0 = *(const float4*)&As[kk][tr * 8];
      float4 a1 = *(const float4*)&As[kk][tr * 8 + 4];
      float4 bv = *(const float4*)&Bs[kk][tc * 4];
      float a[8] = {a0.x, a0.y, a0.z, a0.w, a1.x, a1.y, a1.z, a1.w};
      float b[4] = {bv.x, bv.y, bv.z, bv.w};
#pragma unroll
      for (int i = 0; i < 8; ++i)
#pragma unroll
        for (int j = 0; j < 4; ++j)
          acc[i][j] = fmaf(a[i], b[j], acc[i][j]);
    }
    __syncthreads();
  }
#pragma unroll
  for (int i = 0; i < 8; ++i) {
    int r = bm + tr * 8 + i;
    if (r < M) {
      h4 v;
      v.x = __float2half(acc[i][0]);
      v.y = __float2half(acc[i][1]);
      v.z = __float2half(acc[i][2]);
      v.w = __float2half(acc[i][3]);
      *(h4*)&C[(size_t)r * N + bn + tc * 4] = v;
    }
  }
}

// ---------------- attention coefficients: al_s[n,h], al_d[n,h] ----------------
__global__ __launch_bounds__(256) void k_alpha(const __half* __restrict__ h,
                                               const float* __restrict__ a_s,
                                               const float* __restrict__ a_d,
                                               float* __restrict__ als,
                                               float* __restrict__ ald) {
  int gid = blockIdx.x * blockDim.x + threadIdx.x;
  int n = gid >> 6;
  int lane = threadIdx.x & 63;
  if (n >= NN) return;
  h4 hv4 = *(const h4*)&h[(size_t)n * HCC + lane * 4];
  float hx = __half2float(hv4.x), hy = __half2float(hv4.y);
  float hz = __half2float(hv4.z), hw = __half2float(hv4.w);
  float4 s4 = *(const float4*)&a_s[lane * 4];
  float4 d4 = *(const float4*)&a_d[lane * 4];
  float ss = hx * s4.x + hy * s4.y + hz * s4.z + hw * s4.w;
  float sd = hx * d4.x + hy * d4.y + hz * d4.z + hw * d4.w;
#pragma unroll
  for (int m = 1; m < 16; m <<= 1) {
    ss += __shfl_xor(ss, m);
    sd += __shfl_xor(sd, m);
  }
  if ((lane & 15) == 0) {
    int head = lane >> 4;
    als[n * 4 + head] = ss;
    ald[n * 4 + head] = sd;
  }
}

// ---------------- CSR gather: one wave per dst node ----------------
template<bool CONCAT, bool SELFLOOP, bool FIRST>
__global__ __launch_bounds__(256) void k_gather(const __half* __restrict__ h,
                                                const float* __restrict__ als,
                                                const float* __restrict__ ald,
                                                const int* __restrict__ row_ptr,
                                                const int* __restrict__ csr_src,
                                                const float* __restrict__ bias,
                                                float* __restrict__ outp) {
  int gid = blockIdx.x * blockDim.x + threadIdx.x;
  int n = gid >> 6;
  int lane = threadIdx.x & 63;
  if (n >= NN) return;
  int head = lane >> 4;
  float ad = ald[n * 4 + head];
  int rs = row_ptr[n];
  int re = row_ptr[n + 1];
  float ax = 0.f, ay = 0.f, az = 0.f, aw = 0.f;
  float wsum = 0.f;
  for (int i = rs; i < re; ++i) {
    int s = csr_src[i];
    float lg = als[s * 4 + head] + ad;
    lg = (lg > 0.f) ? lg : NSL * lg;
    float w = __expf(lg);
    wsum += w;
    h4 hv = *(const h4*)&h[(size_t)s * HCC + lane * 4];
    ax = fmaf(w, __half2float(hv.x), ax);
    ay = fmaf(w, __half2float(hv.y), ay);
    az = fmaf(w, __half2float(hv.z), az);
    aw = fmaf(w, __half2float(hv.w), aw);
  }
  if (SELFLOOP) {
    float lg = als[n * 4 + head] + ad;
    lg = (lg > 0.f) ? lg : NSL * lg;
    float w = __expf(lg);
    wsum += w;
    h4 hv = *(const h4*)&h[(size_t)n * HCC + lane * 4];
    ax = fmaf(w, __half2float(hv.x), ax);
    ay = fmaf(w, __half2float(hv.y), ay);
    az = fmaf(w, __half2float(hv.z), az);
    aw = fmaf(w, __half2float(hv.w), aw);
  }
  float inv = 1.0f / (wsum + 1e-16f);
  if (CONCAT) {
    size_t base = (size_t)n * HCC + lane * 4;
    float4 bb = *(const float4*)&bias[lane * 4];
    float4 o;
    if (FIRST) {
      o.x = ax * inv + bb.x;
      o.y = ay * inv + bb.y;
      o.z = az * inv + bb.z;
      o.w = aw * inv + bb.w;
    } else {
      o = *(float4*)&outp[base];
      o.x += ax * inv + bb.x;
      o.y += ay * inv + bb.y;
      o.z += az * inv + bb.z;
      o.w += aw * inv + bb.w;
    }
    *(float4*)&outp[base] = o;
  } else {
    float vx = ax * inv, vy = ay * inv, vz = az * inv, vw = aw * inv;
    vx += __shfl_xor(vx, 16); vy += __shfl_xor(vy, 16);
    vz += __shfl_xor(vz, 16); vw += __shfl_xor(vw, 16);
    vx += __shfl_xor(vx, 32); vy += __shfl_xor(vy, 32);
    vz += __shfl_xor(vz, 32); vw += __shfl_xor(vw, 32);
    if (lane < 16) {
      size_t base = (size_t)n * OC + lane * 4;
      float4 bb = *(const float4*)&bias[lane * 4];
      float4 o;
      if (FIRST) {
        o.x = 0.25f * vx + bb.x;
        o.y = 0.25f * vy + bb.y;
        o.z = 0.25f * vz + bb.z;
        o.w = 0.25f * vw + bb.w;
      } else {
        o = *(float4*)&outp[base];
        o.x += 0.25f * vx + bb.x;
        o.y += 0.25f * vy + bb.y;
        o.z += 0.25f * vz + bb.z;
        o.w += 0.25f * vw + bb.w;
      }
      *(float4*)&outp[base] = o;
    }
  }
}

// ---------------- final: out = relu(out2) @ Wl + bl ----------------
__global__ __launch_bounds__(256) void k_final(const float* __restrict__ out2,
                                               const float* __restrict__ Wl,
                                               const float* __restrict__ bl,
                                               float* __restrict__ outp) {
  __shared__ float Ws[64 * 64];
  __shared__ float bs[64];
  int tid = threadIdx.x;
  for (int i = tid; i < 4096; i += 256) Ws[i] = Wl[i];
  if (tid < 64) bs[tid] = bl[tid];
  __syncthreads();
  int r = blockIdx.x * 4 + (tid >> 6);
  int c = tid & 63;
  if (r >= NN) return;
  const float* xr = &out2[(size_t)r * OC];
  float acc = bs[c];
#pragma unroll
  for (int k = 0; k < 64; ++k) {
    float xv = xr[k];
    xv = (xv > 0.f) ? xv : 0.f;
    acc = fmaf(xv, Ws[k * 64 + c], acc);
  }
  outp[(size_t)r * OC + c] = acc;
}

extern "C" void kernel_launch(void* const* d_in, const int* in_sizes, int n_in,
                              void* d_out, int out_size, void* d_ws, size_t ws_size,
                              hipStream_t stream) {
  const float* x   = (const float*)d_in[0];
  const int* e_b   = (const int*)d_in[1];
  const int* e_sp  = (const int*)d_in[2];
  const int* e_si  = (const int*)d_in[3];
  const float* W1  = (const float*)d_in[4];
  const float* a1s = (const float*)d_in[5];
  const float* a1d = (const float*)d_in[6];
  const float* b1  = (const float*)d_in[7];
  const float* W2  = (const float*)d_in[8];
  const float* a2s = (const float*)d_in[9];
  const float* a2d = (const float*)d_in[10];
  const float* b2  = (const float*)d_in[11];
  const float* Wl  = (const float*)d_in[12];
  const float* bl  = (const float*)d_in[13];
  float* out = (float*)d_out;

  char* ws = (char*)d_ws;
  size_t off = 0;
  auto alloc = [&](size_t b) {
    char* p = ws + off;
    off += (b + 255) & ~(size_t)255;
    return p;
  };
  __half* h   = (__half*)alloc((size_t)NN * HCC * 2);
  float* out1 = (float*)alloc((size_t)NN * HCC * 4);
  float* out2 = (float*)alloc((size_t)NN * OC * 4);
  float* als  = (float*)alloc((size_t)NN * 4 * 4);
  float* ald  = (float*)alloc((size_t)NN * 4 * 4);
  int* deg    = (int*)alloc((size_t)NN * 4);
  int* cursor = (int*)alloc((size_t)(NN + 1) * 4);
  int* rp[3];
  int* cs[3];
  for (int r = 0; r < 3; ++r) {
    rp[r] = (int*)alloc((size_t)(NN + 1) * 4);
    cs[r] = (int*)alloc((size_t)NE * 4);
  }

  const int* edges[3] = {e_b, e_sp, e_si};

  // CSR build (shared by both layers)
  for (int r = 0; r < 3; ++r) {
    hipMemsetAsync(deg, 0, (size_t)NN * 4, stream);
    k_hist<<<1024, 256, 0, stream>>>(edges[r] + NE, deg, NE);
    k_scan<<<1, 1024, 0, stream>>>(deg, rp[r], cursor, NN);
    k_scatter<<<1024, 256, 0, stream>>>(edges[r], edges[r] + NE, cursor, cs[r], NE);
  }

  dim3 ggrid(HCC / 64, (NN + 127) / 128);
  const int ablocks = (NN * 64) / 256;  // 12500

  // layer 1 (concat)
  for (int r = 0; r < 3; ++r) {
    k_gemm<false><<<ggrid, 256, 0, stream>>>(x, W1 + (size_t)r * FIN * HCC, h, NN, HCC, FIN);
    k_alpha<<<ablocks, 256, 0, stream>>>(h, a1s + r * HCC, a1d + r * HCC, als, ald);
    if (r == 0)
      k_gather<true, false, true><<<ablocks, 256, 0, stream>>>(h, als, ald, rp[r], cs[r], b1 + r * HCC, out1);
    else
      k_gather<true, true, false><<<ablocks, 256, 0, stream>>>(h, als, ald, rp[r], cs[r], b1 + r * HCC, out1);
  }
  // layer 2 (mean over heads); relu on layer-1 output fused into GEMM A-load
  for (int r = 0; r < 3; ++r) {
    k_gemm<true><<<ggrid, 256, 0, stream>>>(out1, W2 + (size_t)r * HCC * HCC, h, NN, HCC, HCC);
    k_alpha<<<ablocks, 256, 0, stream>>>(h, a2s + r * HCC, a2d + r * HCC, als, ald);
    if (r == 0)
      k_gather<false, false, true><<<ablocks, 256, 0, stream>>>(h, als, ald, rp[r], cs[r], b2 + r * OC, out2);
    else
      k_gather<false, true, false><<<ablocks, 256, 0, stream>>>(h, als, ald, rp[r], cs[r], b2 + r * OC, out2);
  }
  // final linear (relu on out2 fused)
  k_final<<<(NN + 3) / 4, 256, 0, stream>>>(out2, Wl, bl, out);
}

// Round 3
// 1523.301 us; speedup vs baseline: 1.2624x; 1.1403x over previous
//
#include <hip/hip_runtime.h>
#include <hip/hip_bf16.h>
#include <hip/hip_fp16.h>

#define NN 50000
#define NE 800000
#define FIN 128
#define HCC 256   // HEADS*HID
#define OC 64
#define NSL 0.2f
#define NT3 (3 * NN)

typedef __attribute__((ext_vector_type(8))) short sh8;
typedef __attribute__((ext_vector_type(4))) float f32x4;

struct __attribute__((aligned(8))) h4 { __half x, y, z, w; };

__device__ __forceinline__ unsigned short bf_rne(float f) {
  unsigned u = __float_as_uint(f);
  u += 0x7FFF + ((u >> 16) & 1);
  return (unsigned short)(u >> 16);
}

// ---------------- weight pre-split: W[r][k][n] -> Wt_hi/lo[r][n][k] (bf16) ----------------
__global__ __launch_bounds__(256) void k_prep(const float* __restrict__ W,
                                              short* __restrict__ Wh,
                                              short* __restrict__ Wl_, int K) {
  int total = 3 * K * 256;
  int i = blockIdx.x * 256 + threadIdx.x;
  if (i >= total) return;
  int r = i / (K * 256);
  int rem = i - r * K * 256;
  int k = rem >> 8;
  int n = rem & 255;
  float f = W[i];
  unsigned short hb = bf_rne(f);
  float hf = __uint_as_float(((unsigned)hb) << 16);
  unsigned short lb = bf_rne(f - hf);
  size_t o = ((size_t)r * 256 + n) * K + k;
  Wh[o] = (short)hb;
  Wl_[o] = (short)lb;
}

// ---------------- CSR build ----------------
__global__ void k_hist(const int* __restrict__ dst, int* __restrict__ deg, int n) {
  int i = blockIdx.x * blockDim.x + threadIdx.x;
  int st = gridDim.x * blockDim.x;
  for (; i < n; i += st) atomicAdd(&deg[dst[i]], 1);
}

__global__ __launch_bounds__(1024) void k_bsum(const int* __restrict__ deg3,
                                               int* __restrict__ bsum) {
  __shared__ int s[1024];
  int t = threadIdx.x;
  int i = blockIdx.x * 1024 + t;
  s[t] = (i < NT3) ? deg3[i] : 0;
  __syncthreads();
  for (int off = 512; off > 0; off >>= 1) {
    if (t < off) s[t] += s[t + off];
    __syncthreads();
  }
  if (t == 0) bsum[blockIdx.x] = s[0];
}

__global__ __launch_bounds__(256) void k_scan2(const int* __restrict__ bsum,
                                               int* __restrict__ boffs, int nb) {
  __shared__ int s[256];
  int t = threadIdx.x;
  int v = (t < nb) ? bsum[t] : 0;
  s[t] = v;
  __syncthreads();
  for (int off = 1; off < 256; off <<= 1) {
    int x = (t >= off) ? s[t - off] : 0;
    __syncthreads();
    s[t] += x;
    __syncthreads();
  }
  if (t < nb) boffs[t] = s[t] - v;  // exclusive
}

__global__ __launch_bounds__(1024) void k_rowptr(const int* __restrict__ deg3,
                                                 const int* __restrict__ boffs,
                                                 int* __restrict__ rpA,     // [3][NN+1]
                                                 int* __restrict__ cursor3) // [3*NN]
{
  __shared__ int s[1024];
  int t = threadIdx.x;
  int i = blockIdx.x * 1024 + t;
  int d = (i < NT3) ? deg3[i] : 0;
  s[t] = d;
  __syncthreads();
  for (int off = 1; off < 1024; off <<= 1) {
    int x = (t >= off) ? s[t - off] : 0;
    __syncthreads();
    s[t] += x;
    __syncthreads();
  }
  if (i < NT3) {
    int excl = boffs[blockIdx.x] + s[t] - d;
    int r = (i < NN) ? 0 : ((i < 2 * NN) ? 1 : 2);
    int n = i - r * NN;
    int val = excl - r * NE;
    rpA[r * (NN + 1) + n] = val;
    cursor3[i] = val;
  }
  if (blockIdx.x == 0 && t < 3) rpA[t * (NN + 1) + NN] = NE;
}

__global__ void k_scatter(const int* __restrict__ srcv, const int* __restrict__ dstv,
                          int* __restrict__ cursor, int* __restrict__ csr_src, int n) {
  int i = blockIdx.x * blockDim.x + threadIdx.x;
  int st = gridDim.x * blockDim.x;
  for (; i < n; i += st) {
    int pos = atomicAdd(&cursor[dstv[i]], 1);
    csr_src[pos] = srcv[i];
  }
}

// ---------------- split-bf16 MFMA GEMM, alpha fused ----------------
// C = A[M,KK] @ B[KK,256]; B pre-split/transposed: Bh/Bl [256][KK] bf16.
// Block: 4 waves, each wave 16 rows x 256 cols (16 MFMA tiles), no LDS.
// Epilogue: h (fp16) + als/ald (fp32) per row.
template<int KK, bool RELU>
__global__ __launch_bounds__(256) void k_mgemm(const float* __restrict__ A,
                                               const short* __restrict__ Bh,
                                               const short* __restrict__ Bl,
                                               const float* __restrict__ asf,
                                               const float* __restrict__ adf,
                                               __half* __restrict__ hout,
                                               float* __restrict__ als,
                                               float* __restrict__ ald, int M) {
  const int tid = threadIdx.x;
  const int lane = tid & 63;
  const int w = tid >> 6;
  const int l15 = lane & 15;
  const int lk = lane >> 4;
  const int base = blockIdx.x * 64 + w * 16;

  f32x4 acc[16];
#pragma unroll
  for (int i = 0; i < 16; ++i) acc[i] = (f32x4){0.f, 0.f, 0.f, 0.f};

  const int rowA = base + l15;
  const bool aok = rowA < M;
  const float* ap = A + (size_t)rowA * KK;

#pragma unroll
  for (int kt = 0; kt < KK; kt += 32) {
    const int k0 = kt + lk * 8;
    float4 x0 = make_float4(0.f, 0.f, 0.f, 0.f), x1 = x0;
    if (aok) {
      x0 = *(const float4*)(ap + k0);
      x1 = *(const float4*)(ap + k0 + 4);
    }
    float fa[8] = {x0.x, x0.y, x0.z, x0.w, x1.x, x1.y, x1.z, x1.w};
    sh8 ahi, alo;
#pragma unroll
    for (int j = 0; j < 8; ++j) {
      float f = fa[j];
      if (RELU) f = fmaxf(f, 0.f);
      unsigned short hb = bf_rne(f);
      float hf = __uint_as_float(((unsigned)hb) << 16);
      unsigned short lb = bf_rne(f - hf);
      ahi[j] = (short)hb;
      alo[j] = (short)lb;
    }
#pragma unroll
    for (int nt = 0; nt < 16; ++nt) {
      const size_t bo = ((size_t)(nt * 16 + l15)) * KK + k0;
      sh8 bhi = *(const sh8*)(Bh + bo);
      sh8 blo = *(const sh8*)(Bl + bo);
      acc[nt] = __builtin_amdgcn_mfma_f32_16x16x32_bf16(ahi, bhi, acc[nt], 0, 0, 0);
      acc[nt] = __builtin_amdgcn_mfma_f32_16x16x32_bf16(alo, bhi, acc[nt], 0, 0, 0);
      acc[nt] = __builtin_amdgcn_mfma_f32_16x16x32_bf16(ahi, blo, acc[nt], 0, 0, 0);
    }
  }

  // epilogue: h store + fused alpha
  float asr[16], adr[16];
#pragma unroll
  for (int nt = 0; nt < 16; ++nt) {
    int c = nt * 16 + l15;
    asr[nt] = asf[c];
    adr[nt] = adf[c];
  }
#pragma unroll
  for (int v = 0; v < 4; ++v) {
    int row = base + lk * 4 + v;
    bool rok = row < M;
    float s0 = 0, s1 = 0, s2 = 0, s3 = 0, d0 = 0, d1 = 0, d2 = 0, d3 = 0;
    __half* hp = hout + (size_t)row * 256 + l15;
#pragma unroll
    for (int nt = 0; nt < 16; ++nt) {
      float dv = acc[nt][v];
      if (rok) hp[nt * 16] = __float2half(dv);
      float ps = dv * asr[nt], pd = dv * adr[nt];
      if (nt < 4)       { s0 += ps; d0 += pd; }
      else if (nt < 8)  { s1 += ps; d1 += pd; }
      else if (nt < 12) { s2 += ps; d2 += pd; }
      else              { s3 += ps; d3 += pd; }
    }
#pragma unroll
    for (int m = 1; m < 16; m <<= 1) {
      s0 += __shfl_xor(s0, m); s1 += __shfl_xor(s1, m);
      s2 += __shfl_xor(s2, m); s3 += __shfl_xor(s3, m);
      d0 += __shfl_xor(d0, m); d1 += __shfl_xor(d1, m);
      d2 += __shfl_xor(d2, m); d3 += __shfl_xor(d3, m);
    }
    if (rok && l15 == 0) {
      *(float4*)(als + (size_t)row * 4) = make_float4(s0, s1, s2, s3);
      *(float4*)(ald + (size_t)row * 4) = make_float4(d0, d1, d2, d3);
    }
  }
}

// ---------------- CSR gather: one wave per dst node ----------------
template<bool CONCAT, bool SELFLOOP, bool FIRST>
__global__ __launch_bounds__(256) void k_gather(const __half* __restrict__ h,
                                                const float* __restrict__ als,
                                                const float* __restrict__ ald,
                                                const int* __restrict__ row_ptr,
                                                const int* __restrict__ csr_src,
                                                const float* __restrict__ bias,
                                                float* __restrict__ outp) {
  int gid = blockIdx.x * blockDim.x + threadIdx.x;
  int n = gid >> 6;
  int lane = threadIdx.x & 63;
  if (n >= NN) return;
  int head = lane >> 4;
  float ad = ald[n * 4 + head];
  int rs = row_ptr[n];
  int re = row_ptr[n + 1];
  float ax = 0.f, ay = 0.f, az = 0.f, aw = 0.f;
  float wsum = 0.f;
  for (int i = rs; i < re; ++i) {
    int s = csr_src[i];
    float lg = als[s * 4 + head] + ad;
    lg = (lg > 0.f) ? lg : NSL * lg;
    float w = __expf(lg);
    wsum += w;
    h4 hv = *(const h4*)&h[(size_t)s * HCC + lane * 4];
    ax = fmaf(w, __half2float(hv.x), ax);
    ay = fmaf(w, __half2float(hv.y), ay);
    az = fmaf(w, __half2float(hv.z), az);
    aw = fmaf(w, __half2float(hv.w), aw);
  }
  if (SELFLOOP) {
    float lg = als[n * 4 + head] + ad;
    lg = (lg > 0.f) ? lg : NSL * lg;
    float w = __expf(lg);
    wsum += w;
    h4 hv = *(const h4*)&h[(size_t)n * HCC + lane * 4];
    ax = fmaf(w, __half2float(hv.x), ax);
    ay = fmaf(w, __half2float(hv.y), ay);
    az = fmaf(w, __half2float(hv.z), az);
    aw = fmaf(w, __half2float(hv.w), aw);
  }
  float inv = 1.0f / (wsum + 1e-16f);
  if (CONCAT) {
    size_t base = (size_t)n * HCC + lane * 4;
    float4 bb = *(const float4*)&bias[lane * 4];
    float4 o;
    if (FIRST) {
      o.x = ax * inv + bb.x;
      o.y = ay * inv + bb.y;
      o.z = az * inv + bb.z;
      o.w = aw * inv + bb.w;
    } else {
      o = *(float4*)&outp[base];
      o.x += ax * inv + bb.x;
      o.y += ay * inv + bb.y;
      o.z += az * inv + bb.z;
      o.w += aw * inv + bb.w;
    }
    *(float4*)&outp[base] = o;
  } else {
    float vx = ax * inv, vy = ay * inv, vz = az * inv, vw = aw * inv;
    vx += __shfl_xor(vx, 16); vy += __shfl_xor(vy, 16);
    vz += __shfl_xor(vz, 16); vw += __shfl_xor(vw, 16);
    vx += __shfl_xor(vx, 32); vy += __shfl_xor(vy, 32);
    vz += __shfl_xor(vz, 32); vw += __shfl_xor(vw, 32);
    if (lane < 16) {
      size_t base = (size_t)n * OC + lane * 4;
      float4 bb = *(const float4*)&bias[lane * 4];
      float4 o;
      if (FIRST) {
        o.x = 0.25f * vx + bb.x;
        o.y = 0.25f * vy + bb.y;
        o.z = 0.25f * vz + bb.z;
        o.w = 0.25f * vw + bb.w;
      } else {
        o = *(float4*)&outp[base];
        o.x += 0.25f * vx + bb.x;
        o.y += 0.25f * vy + bb.y;
        o.z += 0.25f * vz + bb.z;
        o.w += 0.25f * vw + bb.w;
      }
      *(float4*)&outp[base] = o;
    }
  }
}

// ---------------- final: out = relu(out2) @ Wl + bl ----------------
__global__ __launch_bounds__(256) void k_final(const float* __restrict__ out2,
                                               const float* __restrict__ Wl,
                                               const float* __restrict__ bl,
                                               float* __restrict__ outp) {
  __shared__ float Ws[64 * 64];
  __shared__ float bs[64];
  int tid = threadIdx.x;
  for (int i = tid; i < 4096; i += 256) Ws[i] = Wl[i];
  if (tid < 64) bs[tid] = bl[tid];
  __syncthreads();
  int r = blockIdx.x * 4 + (tid >> 6);
  int c = tid & 63;
  if (r >= NN) return;
  const float* xr = &out2[(size_t)r * OC];
  float acc = bs[c];
#pragma unroll
  for (int k = 0; k < 64; ++k) {
    float xv = xr[k];
    xv = (xv > 0.f) ? xv : 0.f;
    acc = fmaf(xv, Ws[k * 64 + c], acc);
  }
  outp[(size_t)r * OC + c] = acc;
}

extern "C" void kernel_launch(void* const* d_in, const int* in_sizes, int n_in,
                              void* d_out, int out_size, void* d_ws, size_t ws_size,
                              hipStream_t stream) {
  const float* x   = (const float*)d_in[0];
  const int* e_b   = (const int*)d_in[1];
  const int* e_sp  = (const int*)d_in[2];
  const int* e_si  = (const int*)d_in[3];
  const float* W1  = (const float*)d_in[4];
  const float* a1s = (const float*)d_in[5];
  const float* a1d = (const float*)d_in[6];
  const float* b1  = (const float*)d_in[7];
  const float* W2  = (const float*)d_in[8];
  const float* a2s = (const float*)d_in[9];
  const float* a2d = (const float*)d_in[10];
  const float* b2  = (const float*)d_in[11];
  const float* Wl  = (const float*)d_in[12];
  const float* bl  = (const float*)d_in[13];
  float* out = (float*)d_out;

  char* ws = (char*)d_ws;
  size_t off = 0;
  auto alloc = [&](size_t b) {
    char* p = ws + off;
    off += (b + 255) & ~(size_t)255;
    return p;
  };
  __half* h   = (__half*)alloc((size_t)NN * HCC * 2);
  float* out1 = (float*)alloc((size_t)NN * HCC * 4);
  float* out2 = (float*)alloc((size_t)NN * OC * 4);
  float* als  = (float*)alloc((size_t)NN * 4 * 4);
  float* ald  = (float*)alloc((size_t)NN * 4 * 4);
  int* deg3   = (int*)alloc((size_t)NT3 * 4);
  int* cursor3= (int*)alloc((size_t)NT3 * 4);
  int* rpA    = (int*)alloc((size_t)3 * (NN + 1) * 4);
  int* bsum   = (int*)alloc(256 * 4);
  int* boffs  = (int*)alloc(256 * 4);
  short* Wt1h = (short*)alloc((size_t)3 * HCC * FIN * 2);
  short* Wt1l = (short*)alloc((size_t)3 * HCC * FIN * 2);
  short* Wt2h = (short*)alloc((size_t)3 * HCC * HCC * 2);
  short* Wt2l = (short*)alloc((size_t)3 * HCC * HCC * 2);
  int* cs[3];
  for (int r = 0; r < 3; ++r) cs[r] = (int*)alloc((size_t)NE * 4);

  const int* edges[3] = {e_b, e_sp, e_si};

  // weight pre-split (tiny)
  k_prep<<<(3 * FIN * 256 + 255) / 256, 256, 0, stream>>>(W1, Wt1h, Wt1l, FIN);
  k_prep<<<(3 * HCC * 256 + 255) / 256, 256, 0, stream>>>(W2, Wt2h, Wt2l, HCC);

  // CSR build: 3 relations fused through one scan
  hipMemsetAsync(deg3, 0, (size_t)NT3 * 4, stream);
  for (int r = 0; r < 3; ++r)
    k_hist<<<1024, 256, 0, stream>>>(edges[r] + NE, deg3 + r * NN, NE);
  const int NB = (NT3 + 1023) / 1024;  // 147
  k_bsum<<<NB, 1024, 0, stream>>>(deg3, bsum);
  k_scan2<<<1, 256, 0, stream>>>(bsum, boffs, NB);
  k_rowptr<<<NB, 1024, 0, stream>>>(deg3, boffs, rpA, cursor3);
  for (int r = 0; r < 3; ++r)
    k_scatter<<<1024, 256, 0, stream>>>(edges[r], edges[r] + NE, cursor3 + r * NN, cs[r], NE);

  const int gblocks = (NN + 63) / 64;  // 782
  const int ablocks = (NN * 64) / 256; // 12500

  // layer 1 (concat)
  for (int r = 0; r < 3; ++r) {
    k_mgemm<FIN, false><<<gblocks, 256, 0, stream>>>(
        x, Wt1h + (size_t)r * HCC * FIN, Wt1l + (size_t)r * HCC * FIN,
        a1s + r * HCC, a1d + r * HCC, h, als, ald, NN);
    if (r == 0)
      k_gather<true, false, true><<<ablocks, 256, 0, stream>>>(h, als, ald, rpA + r * (NN + 1), cs[r], b1 + r * HCC, out1);
    else
      k_gather<true, true, false><<<ablocks, 256, 0, stream>>>(h, als, ald, rpA + r * (NN + 1), cs[r], b1 + r * HCC, out1);
  }
  // layer 2 (mean over heads); relu fused into GEMM A-conversion
  for (int r = 0; r < 3; ++r) {
    k_mgemm<HCC, true><<<gblocks, 256, 0, stream>>>(
        out1, Wt2h + (size_t)r * HCC * HCC, Wt2l + (size_t)r * HCC * HCC,
        a2s + r * HCC, a2d + r * HCC, h, als, ald, NN);
    if (r == 0)
      k_gather<false, false, true><<<ablocks, 256, 0, stream>>>(h, als, ald, rpA + r * (NN + 1), cs[r], b2 + r * OC, out2);
    else
      k_gather<false, true, false><<<ablocks, 256, 0, stream>>>(h, als, ald, rpA + r * (NN + 1), cs[r], b2 + r * OC, out2);
  }
  // final linear (relu on out2 fused)
  k_final<<<(NN + 3) / 4, 256, 0, stream>>>(out2, Wl, bl, out);
}

// Round 4
// 1195.125 us; speedup vs baseline: 1.6090x; 1.2746x over previous
//
#include <hip/hip_runtime.h>
#include <hip/hip_bf16.h>
#include <hip/hip_fp16.h>

#define NN 50000
#define NE 800000
#define FIN 128
#define HCC 256   // HEADS*HID
#define OC 64
#define NSL 0.2f
#define NT3 (3 * NN)

typedef __attribute__((ext_vector_type(8))) short sh8;
typedef __attribute__((ext_vector_type(16))) float f32x16;

struct __attribute__((aligned(8))) h4 { __half x, y, z, w; };

__device__ __forceinline__ unsigned short bf_rne(float f) {
  unsigned u = __float_as_uint(f);
  u += 0x7FFF + ((u >> 16) & 1);
  return (unsigned short)(u >> 16);
}

// -------- weight pre-split into chunked-coalesced layout --------
// W:[3][KK][256] fp32 -> out:[3][cb(2)][hl(2)][KK/8][c(128)][8] bf16
template<int KK>
__global__ __launch_bounds__(256) void k_prep(const float* __restrict__ W,
                                              short* __restrict__ out) {
  int i = blockIdx.x * 256 + threadIdx.x;
  if (i >= 3 * KK * 256) return;
  int r = i / (KK * 256);
  int rem = i - r * KK * 256;
  int k = rem >> 8;
  int n = rem & 255;
  float f = W[i];
  unsigned short hb = bf_rne(f);
  float hf = __uint_as_float(((unsigned)hb) << 16);
  unsigned short lb = bf_rne(f - hf);
  int cb = n >> 7, c = n & 127, ks8 = k >> 3, kj = k & 7;
  size_t base = (size_t)r * 4 * KK * 128;
  size_t oh = base + ((size_t)((cb * 2 + 0) * (KK / 8) + ks8) * 128 + c) * 8 + kj;
  size_t ol = base + ((size_t)((cb * 2 + 1) * (KK / 8) + ks8) * 128 + c) * 8 + kj;
  out[oh] = (short)hb;
  out[ol] = (short)lb;
}

// ---------------- CSR build ----------------
__global__ void k_hist(const int* __restrict__ dst, int* __restrict__ deg, int n) {
  int i = blockIdx.x * blockDim.x + threadIdx.x;
  int st = gridDim.x * blockDim.x;
  for (; i < n; i += st) atomicAdd(&deg[dst[i]], 1);
}

__global__ __launch_bounds__(1024) void k_bsum(const int* __restrict__ deg3,
                                               int* __restrict__ bsum) {
  __shared__ int s[1024];
  int t = threadIdx.x;
  int i = blockIdx.x * 1024 + t;
  s[t] = (i < NT3) ? deg3[i] : 0;
  __syncthreads();
  for (int off = 512; off > 0; off >>= 1) {
    if (t < off) s[t] += s[t + off];
    __syncthreads();
  }
  if (t == 0) bsum[blockIdx.x] = s[0];
}

__global__ __launch_bounds__(256) void k_scan2(const int* __restrict__ bsum,
                                               int* __restrict__ boffs, int nb) {
  __shared__ int s[256];
  int t = threadIdx.x;
  int v = (t < nb) ? bsum[t] : 0;
  s[t] = v;
  __syncthreads();
  for (int off = 1; off < 256; off <<= 1) {
    int x = (t >= off) ? s[t - off] : 0;
    __syncthreads();
    s[t] += x;
    __syncthreads();
  }
  if (t < nb) boffs[t] = s[t] - v;  // exclusive
}

__global__ __launch_bounds__(1024) void k_rowptr(const int* __restrict__ deg3,
                                                 const int* __restrict__ boffs,
                                                 int* __restrict__ rpA,
                                                 int* __restrict__ cursor3) {
  __shared__ int s[1024];
  int t = threadIdx.x;
  int i = blockIdx.x * 1024 + t;
  int d = (i < NT3) ? deg3[i] : 0;
  s[t] = d;
  __syncthreads();
  for (int off = 1; off < 1024; off <<= 1) {
    int x = (t >= off) ? s[t - off] : 0;
    __syncthreads();
    s[t] += x;
    __syncthreads();
  }
  if (i < NT3) {
    int excl = boffs[blockIdx.x] + s[t] - d;
    int r = (i < NN) ? 0 : ((i < 2 * NN) ? 1 : 2);
    int n = i - r * NN;
    int val = excl - r * NE;
    rpA[r * (NN + 1) + n] = val;
    cursor3[i] = val;
  }
  if (blockIdx.x == 0 && t < 3) rpA[t * (NN + 1) + NN] = NE;
}

__global__ void k_scatter(const int* __restrict__ srcv, const int* __restrict__ dstv,
                          int* __restrict__ cursor, int* __restrict__ csr_src, int n) {
  int i = blockIdx.x * blockDim.x + threadIdx.x;
  int st = gridDim.x * blockDim.x;
  for (; i < n; i += st) {
    int pos = atomicAdd(&cursor[dstv[i]], 1);
    csr_src[pos] = srcv[i];
  }
}

// -------- split-bf16 MFMA GEMM (32x32x16 tiles), alpha fused --------
// Block: 4 waves as 2x2: wave (w&1) -> 32-row group, (w>>1) -> 128-col half.
// BM=64. B from chunked global layout (L2-resident), A per-lane from global.
template<int KK, bool RELU>
__global__ __launch_bounds__(256) void k_mgemm(const float* __restrict__ A,
                                               const short* __restrict__ Bc,
                                               const float* __restrict__ asf,
                                               const float* __restrict__ adf,
                                               __half* __restrict__ hout,
                                               float* __restrict__ als,
                                               float* __restrict__ ald, int M) {
  const int tid = threadIdx.x;
  const int lane = tid & 63;
  const int w = tid >> 6;
  const int l31 = lane & 31;
  const int lg = lane >> 5;
  const int wrow = blockIdx.x * 64 + (w & 1) * 32;
  const int ch = w >> 1;

  f32x16 acc[4];
#pragma unroll
  for (int t = 0; t < 4; ++t) acc[t] = (f32x16)(0.f);

  const int r = wrow + l31;
  const bool aok = r < M;
  const float* ap = A + (size_t)r * KK;
  const short* bh = Bc + (size_t)(ch * 2 + 0) * KK * 128 + l31 * 8;
  const short* bl = Bc + (size_t)(ch * 2 + 1) * KK * 128 + l31 * 8;

#pragma unroll 2
  for (int kst = 0; kst < KK / 16; ++kst) {
    const int k0 = kst * 16 + lg * 8;
    float4 x0 = make_float4(0.f, 0.f, 0.f, 0.f), x1 = x0;
    if (aok) {
      x0 = *(const float4*)(ap + k0);
      x1 = *(const float4*)(ap + k0 + 4);
    }
    const int ks8 = kst * 2 + lg;
    const short* bhp = bh + (size_t)ks8 * 1024;
    const short* blp = bl + (size_t)ks8 * 1024;
    sh8 bhf[4], blf[4];
#pragma unroll
    for (int t = 0; t < 4; ++t) {
      bhf[t] = *(const sh8*)(bhp + t * 256);
      blf[t] = *(const sh8*)(blp + t * 256);
    }
    float fa[8] = {x0.x, x0.y, x0.z, x0.w, x1.x, x1.y, x1.z, x1.w};
    sh8 ahi, alo;
#pragma unroll
    for (int j = 0; j < 8; ++j) {
      float f = fa[j];
      if (RELU) f = fmaxf(f, 0.f);
      unsigned short hb = bf_rne(f);
      float hf = __uint_as_float(((unsigned)hb) << 16);
      unsigned short lb = bf_rne(f - hf);
      ahi[j] = (short)hb;
      alo[j] = (short)lb;
    }
#pragma unroll
    for (int t = 0; t < 4; ++t) {
      acc[t] = __builtin_amdgcn_mfma_f32_32x32x16_bf16(ahi, bhf[t], acc[t], 0, 0, 0);
      acc[t] = __builtin_amdgcn_mfma_f32_32x32x16_bf16(alo, bhf[t], acc[t], 0, 0, 0);
      acc[t] = __builtin_amdgcn_mfma_f32_32x32x16_bf16(ahi, blf[t], acc[t], 0, 0, 0);
    }
  }

  // epilogue: h (fp16) store + fused alpha (2 heads per col-half)
  float asr[4], adr[4];
#pragma unroll
  for (int t = 0; t < 4; ++t) {
    int col = ch * 128 + t * 32 + l31;
    asr[t] = asf[col];
    adr[t] = adf[col];
  }
#pragma unroll
  for (int v = 0; v < 16; ++v) {
    const int rl = (v & 3) + 8 * (v >> 2) + 4 * lg;
    const int row = wrow + rl;
    const bool rok = row < M;
    float s0 = 0.f, s1 = 0.f, d0 = 0.f, d1 = 0.f;
    __half* hp = hout + (size_t)row * 256 + ch * 128 + l31;
#pragma unroll
    for (int t = 0; t < 4; ++t) {
      float dv = acc[t][v];
      if (rok) hp[t * 32] = __float2half(dv);
      if (t < 2) { s0 += dv * asr[t]; d0 += dv * adr[t]; }
      else       { s1 += dv * asr[t]; d1 += dv * adr[t]; }
    }
#pragma unroll
    for (int m = 1; m < 32; m <<= 1) {
      s0 += __shfl_xor(s0, m);
      s1 += __shfl_xor(s1, m);
      d0 += __shfl_xor(d0, m);
      d1 += __shfl_xor(d1, m);
    }
    if (rok && l31 == 0) {
      *(float2*)(als + (size_t)row * 4 + ch * 2) = make_float2(s0, s1);
      *(float2*)(ald + (size_t)row * 4 + ch * 2) = make_float2(d0, d1);
    }
  }
}

// ---------------- CSR gather: one wave per dst node ----------------
template<bool CONCAT, bool SELFLOOP, bool FIRST>
__global__ __launch_bounds__(256) void k_gather(const __half* __restrict__ h,
                                                const float* __restrict__ als,
                                                const float* __restrict__ ald,
                                                const int* __restrict__ row_ptr,
                                                const int* __restrict__ csr_src,
                                                const float* __restrict__ bias,
                                                float* __restrict__ outp) {
  int gid = blockIdx.x * blockDim.x + threadIdx.x;
  int n = gid >> 6;
  int lane = threadIdx.x & 63;
  if (n >= NN) return;
  int head = lane >> 4;
  float ad = ald[n * 4 + head];
  int rs = row_ptr[n];
  int re = row_ptr[n + 1];
  float ax = 0.f, ay = 0.f, az = 0.f, aw = 0.f;
  float wsum = 0.f;
  for (int i = rs; i < re; ++i) {
    int s = csr_src[i];
    float lg = als[s * 4 + head] + ad;
    lg = (lg > 0.f) ? lg : NSL * lg;
    float w = __expf(lg);
    wsum += w;
    h4 hv = *(const h4*)&h[(size_t)s * HCC + lane * 4];
    ax = fmaf(w, __half2float(hv.x), ax);
    ay = fmaf(w, __half2float(hv.y), ay);
    az = fmaf(w, __half2float(hv.z), az);
    aw = fmaf(w, __half2float(hv.w), aw);
  }
  if (SELFLOOP) {
    float lg = als[n * 4 + head] + ad;
    lg = (lg > 0.f) ? lg : NSL * lg;
    float w = __expf(lg);
    wsum += w;
    h4 hv = *(const h4*)&h[(size_t)n * HCC + lane * 4];
    ax = fmaf(w, __half2float(hv.x), ax);
    ay = fmaf(w, __half2float(hv.y), ay);
    az = fmaf(w, __half2float(hv.z), az);
    aw = fmaf(w, __half2float(hv.w), aw);
  }
  float inv = 1.0f / (wsum + 1e-16f);
  if (CONCAT) {
    size_t base = (size_t)n * HCC + lane * 4;
    float4 bb = *(const float4*)&bias[lane * 4];
    float4 o;
    if (FIRST) {
      o.x = ax * inv + bb.x;
      o.y = ay * inv + bb.y;
      o.z = az * inv + bb.z;
      o.w = aw * inv + bb.w;
    } else {
      o = *(float4*)&outp[base];
      o.x += ax * inv + bb.x;
      o.y += ay * inv + bb.y;
      o.z += az * inv + bb.z;
      o.w += aw * inv + bb.w;
    }
    *(float4*)&outp[base] = o;
  } else {
    float vx = ax * inv, vy = ay * inv, vz = az * inv, vw = aw * inv;
    vx += __shfl_xor(vx, 16); vy += __shfl_xor(vy, 16);
    vz += __shfl_xor(vz, 16); vw += __shfl_xor(vw, 16);
    vx += __shfl_xor(vx, 32); vy += __shfl_xor(vy, 32);
    vz += __shfl_xor(vz, 32); vw += __shfl_xor(vw, 32);
    if (lane < 16) {
      size_t base = (size_t)n * OC + lane * 4;
      float4 bb = *(const float4*)&bias[lane * 4];
      float4 o;
      if (FIRST) {
        o.x = 0.25f * vx + bb.x;
        o.y = 0.25f * vy + bb.y;
        o.z = 0.25f * vz + bb.z;
        o.w = 0.25f * vw + bb.w;
      } else {
        o = *(float4*)&outp[base];
        o.x += 0.25f * vx + bb.x;
        o.y += 0.25f * vy + bb.y;
        o.z += 0.25f * vz + bb.z;
        o.w += 0.25f * vw + bb.w;
      }
      *(float4*)&outp[base] = o;
    }
  }
}

// ---------------- final: out = relu(out2) @ Wl + bl ----------------
__global__ __launch_bounds__(256) void k_final(const float* __restrict__ out2,
                                               const float* __restrict__ Wl,
                                               const float* __restrict__ bl,
                                               float* __restrict__ outp) {
  __shared__ float Ws[64 * 64];
  __shared__ float bs[64];
  int tid = threadIdx.x;
  for (int i = tid; i < 4096; i += 256) Ws[i] = Wl[i];
  if (tid < 64) bs[tid] = bl[tid];
  __syncthreads();
  int r = blockIdx.x * 4 + (tid >> 6);
  int c = tid & 63;
  if (r >= NN) return;
  const float* xr = &out2[(size_t)r * OC];
  float acc = bs[c];
#pragma unroll
  for (int k = 0; k < 64; ++k) {
    float xv = xr[k];
    xv = (xv > 0.f) ? xv : 0.f;
    acc = fmaf(xv, Ws[k * 64 + c], acc);
  }
  outp[(size_t)r * OC + c] = acc;
}

extern "C" void kernel_launch(void* const* d_in, const int* in_sizes, int n_in,
                              void* d_out, int out_size, void* d_ws, size_t ws_size,
                              hipStream_t stream) {
  const float* x   = (const float*)d_in[0];
  const int* e_b   = (const int*)d_in[1];
  const int* e_sp  = (const int*)d_in[2];
  const int* e_si  = (const int*)d_in[3];
  const float* W1  = (const float*)d_in[4];
  const float* a1s = (const float*)d_in[5];
  const float* a1d = (const float*)d_in[6];
  const float* b1  = (const float*)d_in[7];
  const float* W2  = (const float*)d_in[8];
  const float* a2s = (const float*)d_in[9];
  const float* a2d = (const float*)d_in[10];
  const float* b2  = (const float*)d_in[11];
  const float* Wl  = (const float*)d_in[12];
  const float* bl  = (const float*)d_in[13];
  float* out = (float*)d_out;

  char* ws = (char*)d_ws;
  size_t off = 0;
  auto alloc = [&](size_t b) {
    char* p = ws + off;
    off += (b + 255) & ~(size_t)255;
    return p;
  };
  __half* h   = (__half*)alloc((size_t)NN * HCC * 2);
  float* out1 = (float*)alloc((size_t)NN * HCC * 4);
  float* out2 = (float*)alloc((size_t)NN * OC * 4);
  float* als  = (float*)alloc((size_t)NN * 4 * 4);
  float* ald  = (float*)alloc((size_t)NN * 4 * 4);
  int* deg3   = (int*)alloc((size_t)NT3 * 4);
  int* cursor3= (int*)alloc((size_t)NT3 * 4);
  int* rpA    = (int*)alloc((size_t)3 * (NN + 1) * 4);
  int* bsum   = (int*)alloc(256 * 4);
  int* boffs  = (int*)alloc(256 * 4);
  short* Wc1  = (short*)alloc((size_t)3 * 4 * FIN * 128 * 2);
  short* Wc2  = (short*)alloc((size_t)3 * 4 * HCC * 128 * 2);
  int* cs[3];
  for (int r = 0; r < 3; ++r) cs[r] = (int*)alloc((size_t)NE * 4);

  const int* edges[3] = {e_b, e_sp, e_si};

  // weight pre-split (tiny)
  k_prep<FIN><<<(3 * FIN * 256 + 255) / 256, 256, 0, stream>>>(W1, Wc1);
  k_prep<HCC><<<(3 * HCC * 256 + 255) / 256, 256, 0, stream>>>(W2, Wc2);

  // CSR build: 3 relations fused through one scan
  hipMemsetAsync(deg3, 0, (size_t)NT3 * 4, stream);
  for (int r = 0; r < 3; ++r)
    k_hist<<<1024, 256, 0, stream>>>(edges[r] + NE, deg3 + r * NN, NE);
  const int NB = (NT3 + 1023) / 1024;  // 147
  k_bsum<<<NB, 1024, 0, stream>>>(deg3, bsum);
  k_scan2<<<1, 256, 0, stream>>>(bsum, boffs, NB);
  k_rowptr<<<NB, 1024, 0, stream>>>(deg3, boffs, rpA, cursor3);
  for (int r = 0; r < 3; ++r)
    k_scatter<<<1024, 256, 0, stream>>>(edges[r], edges[r] + NE, cursor3 + r * NN, cs[r], NE);

  const int gblocks = (NN + 63) / 64;  // 782
  const int ablocks = (NN * 64) / 256; // 12500

  // layer 1 (concat)
  for (int r = 0; r < 3; ++r) {
    k_mgemm<FIN, false><<<gblocks, 256, 0, stream>>>(
        x, Wc1 + (size_t)r * 4 * FIN * 128,
        a1s + r * HCC, a1d + r * HCC, h, als, ald, NN);
    if (r == 0)
      k_gather<true, false, true><<<ablocks, 256, 0, stream>>>(h, als, ald, rpA + r * (NN + 1), cs[r], b1 + r * HCC, out1);
    else
      k_gather<true, true, false><<<ablocks, 256, 0, stream>>>(h, als, ald, rpA + r * (NN + 1), cs[r], b1 + r * HCC, out1);
  }
  // layer 2 (mean over heads); relu fused into GEMM A-conversion
  for (int r = 0; r < 3; ++r) {
    k_mgemm<HCC, true><<<gblocks, 256, 0, stream>>>(
        out1, Wc2 + (size_t)r * 4 * HCC * 128,
        a2s + r * HCC, a2d + r * HCC, h, als, ald, NN);
    if (r == 0)
      k_gather<false, false, true><<<ablocks, 256, 0, stream>>>(h, als, ald, rpA + r * (NN + 1), cs[r], b2 + r * OC, out2);
    else
      k_gather<false, true, false><<<ablocks, 256, 0, stream>>>(h, als, ald, rpA + r * (NN + 1), cs[r], b2 + r * OC, out2);
  }
  // final linear (relu on out2 fused)
  k_final<<<(NN + 3) / 4, 256, 0, stream>>>(out2, Wl, bl, out);
}

// Round 5
// 1001.203 us; speedup vs baseline: 1.9206x; 1.1937x over previous
//
#include <hip/hip_runtime.h>
#include <hip/hip_bf16.h>
#include <hip/hip_fp16.h>

#define NN 50000
#define NE 800000
#define FIN 128
#define HCC 256   // HEADS*HID
#define OC 64
#define NSL 0.2f
#define NT3 (3 * NN)

typedef __attribute__((ext_vector_type(8))) short sh8;
typedef __attribute__((ext_vector_type(16))) float f32x16;

struct __attribute__((aligned(8))) h4 { __half x, y, z, w; };

__device__ __forceinline__ unsigned short bf_rne(float f) {
  unsigned u = __float_as_uint(f);
  u += 0x7FFF + ((u >> 16) & 1);
  return (unsigned short)(u >> 16);
}

__device__ __forceinline__ float edge_w(float lg) {
  lg = (lg > 0.f) ? lg : NSL * lg;
  return __expf(lg);
}

// -------- weight pre-split into chunked-coalesced layout --------
// W:[3][KK][256] fp32 -> out:[3][cb(2)][hl(2)][KK/8][c(128)][8] bf16
template<int KK>
__global__ __launch_bounds__(256) void k_prep(const float* __restrict__ W,
                                              short* __restrict__ out) {
  int i = blockIdx.x * 256 + threadIdx.x;
  if (i >= 3 * KK * 256) return;
  int r = i / (KK * 256);
  int rem = i - r * KK * 256;
  int k = rem >> 8;
  int n = rem & 255;
  float f = W[i];
  unsigned short hb = bf_rne(f);
  float hf = __uint_as_float(((unsigned)hb) << 16);
  unsigned short lb = bf_rne(f - hf);
  int cb = n >> 7, c = n & 127, ks8 = k >> 3, kj = k & 7;
  size_t base = (size_t)r * 4 * KK * 128;
  size_t oh = base + ((size_t)((cb * 2 + 0) * (KK / 8) + ks8) * 128 + c) * 8 + kj;
  size_t ol = base + ((size_t)((cb * 2 + 1) * (KK / 8) + ks8) * 128 + c) * 8 + kj;
  out[oh] = (short)hb;
  out[ol] = (short)lb;
}

// ---------------- CSR build ----------------
__global__ void k_hist(const int* __restrict__ dst, int* __restrict__ deg, int n) {
  int i = blockIdx.x * blockDim.x + threadIdx.x;
  int st = gridDim.x * blockDim.x;
  for (; i < n; i += st) atomicAdd(&deg[dst[i]], 1);
}

__global__ __launch_bounds__(1024) void k_bsum(const int* __restrict__ deg3,
                                               int* __restrict__ bsum) {
  __shared__ int s[1024];
  int t = threadIdx.x;
  int i = blockIdx.x * 1024 + t;
  s[t] = (i < NT3) ? deg3[i] : 0;
  __syncthreads();
  for (int off = 512; off > 0; off >>= 1) {
    if (t < off) s[t] += s[t + off];
    __syncthreads();
  }
  if (t == 0) bsum[blockIdx.x] = s[0];
}

__global__ __launch_bounds__(256) void k_scan2(const int* __restrict__ bsum,
                                               int* __restrict__ boffs, int nb) {
  __shared__ int s[256];
  int t = threadIdx.x;
  int v = (t < nb) ? bsum[t] : 0;
  s[t] = v;
  __syncthreads();
  for (int off = 1; off < 256; off <<= 1) {
    int x = (t >= off) ? s[t - off] : 0;
    __syncthreads();
    s[t] += x;
    __syncthreads();
  }
  if (t < nb) boffs[t] = s[t] - v;  // exclusive
}

__global__ __launch_bounds__(1024) void k_rowptr(const int* __restrict__ deg3,
                                                 const int* __restrict__ boffs,
                                                 int* __restrict__ rpA,
                                                 int* __restrict__ cursor3) {
  __shared__ int s[1024];
  int t = threadIdx.x;
  int i = blockIdx.x * 1024 + t;
  int d = (i < NT3) ? deg3[i] : 0;
  s[t] = d;
  __syncthreads();
  for (int off = 1; off < 1024; off <<= 1) {
    int x = (t >= off) ? s[t - off] : 0;
    __syncthreads();
    s[t] += x;
    __syncthreads();
  }
  if (i < NT3) {
    int excl = boffs[blockIdx.x] + s[t] - d;
    int r = (i < NN) ? 0 : ((i < 2 * NN) ? 1 : 2);
    int n = i - r * NN;
    int val = excl - r * NE;
    rpA[r * (NN + 1) + n] = val;
    cursor3[i] = val;
  }
  if (blockIdx.x == 0 && t < 3) rpA[t * (NN + 1) + NN] = NE;
}

__global__ void k_scatter(const int* __restrict__ srcv, const int* __restrict__ dstv,
                          int* __restrict__ cursor, int* __restrict__ csr_src, int n) {
  int i = blockIdx.x * blockDim.x + threadIdx.x;
  int st = gridDim.x * blockDim.x;
  for (; i < n; i += st) {
    int pos = atomicAdd(&cursor[dstv[i]], 1);
    csr_src[pos] = srcv[i];
  }
}

// -------- split-bf16 MFMA GEMM (32x32x16 tiles), alpha fused --------
template<int KK, bool RELU>
__global__ __launch_bounds__(256) void k_mgemm(const float* __restrict__ A,
                                               const short* __restrict__ Bc,
                                               const float* __restrict__ asf,
                                               const float* __restrict__ adf,
                                               __half* __restrict__ hout,
                                               float* __restrict__ als,
                                               float* __restrict__ ald, int M) {
  const int tid = threadIdx.x;
  const int lane = tid & 63;
  const int w = tid >> 6;
  const int l31 = lane & 31;
  const int lg = lane >> 5;
  const int wrow = blockIdx.x * 64 + (w & 1) * 32;
  const int ch = w >> 1;

  f32x16 acc[4];
#pragma unroll
  for (int t = 0; t < 4; ++t) acc[t] = (f32x16)(0.f);

  const int r = wrow + l31;
  const bool aok = r < M;
  const float* ap = A + (size_t)r * KK;
  const short* bh = Bc + (size_t)(ch * 2 + 0) * KK * 128 + l31 * 8;
  const short* bl = Bc + (size_t)(ch * 2 + 1) * KK * 128 + l31 * 8;

#pragma unroll 2
  for (int kst = 0; kst < KK / 16; ++kst) {
    const int k0 = kst * 16 + lg * 8;
    float4 x0 = make_float4(0.f, 0.f, 0.f, 0.f), x1 = x0;
    if (aok) {
      x0 = *(const float4*)(ap + k0);
      x1 = *(const float4*)(ap + k0 + 4);
    }
    const int ks8 = kst * 2 + lg;
    const short* bhp = bh + (size_t)ks8 * 1024;
    const short* blp = bl + (size_t)ks8 * 1024;
    sh8 bhf[4], blf[4];
#pragma unroll
    for (int t = 0; t < 4; ++t) {
      bhf[t] = *(const sh8*)(bhp + t * 256);
      blf[t] = *(const sh8*)(blp + t * 256);
    }
    float fa[8] = {x0.x, x0.y, x0.z, x0.w, x1.x, x1.y, x1.z, x1.w};
    sh8 ahi, alo;
#pragma unroll
    for (int j = 0; j < 8; ++j) {
      float f = fa[j];
      if (RELU) f = fmaxf(f, 0.f);
      unsigned short hb = bf_rne(f);
      float hf = __uint_as_float(((unsigned)hb) << 16);
      unsigned short lb = bf_rne(f - hf);
      ahi[j] = (short)hb;
      alo[j] = (short)lb;
    }
#pragma unroll
    for (int t = 0; t < 4; ++t) {
      acc[t] = __builtin_amdgcn_mfma_f32_32x32x16_bf16(ahi, bhf[t], acc[t], 0, 0, 0);
      acc[t] = __builtin_amdgcn_mfma_f32_32x32x16_bf16(alo, bhf[t], acc[t], 0, 0, 0);
      acc[t] = __builtin_amdgcn_mfma_f32_32x32x16_bf16(ahi, blf[t], acc[t], 0, 0, 0);
    }
  }

  // epilogue: h (fp16) store + fused alpha (2 heads per col-half)
  float asr[4], adr[4];
#pragma unroll
  for (int t = 0; t < 4; ++t) {
    int col = ch * 128 + t * 32 + l31;
    asr[t] = asf[col];
    adr[t] = adf[col];
  }
#pragma unroll
  for (int v = 0; v < 16; ++v) {
    const int rl = (v & 3) + 8 * (v >> 2) + 4 * lg;
    const int row = wrow + rl;
    const bool rok = row < M;
    float s0 = 0.f, s1 = 0.f, d0 = 0.f, d1 = 0.f;
    __half* hp = hout + (size_t)row * 256 + ch * 128 + l31;
#pragma unroll
    for (int t = 0; t < 4; ++t) {
      float dv = acc[t][v];
      if (rok) hp[t * 32] = __float2half(dv);
      if (t < 2) { s0 += dv * asr[t]; d0 += dv * adr[t]; }
      else       { s1 += dv * asr[t]; d1 += dv * adr[t]; }
    }
#pragma unroll
    for (int m = 1; m < 32; m <<= 1) {
      s0 += __shfl_xor(s0, m);
      s1 += __shfl_xor(s1, m);
      d0 += __shfl_xor(d0, m);
      d1 += __shfl_xor(d1, m);
    }
    if (rok && l31 == 0) {
      *(float2*)(als + (size_t)row * 4 + ch * 2) = make_float2(s0, s1);
      *(float2*)(ald + (size_t)row * 4 + ch * 2) = make_float2(d0, d1);
    }
  }
}

// ---------------- CSR gather: one wave per dst node, 4-deep prefetch ----------------
template<bool CONCAT, bool SELFLOOP, bool FIRST>
__global__ __launch_bounds__(256) void k_gather(const __half* __restrict__ h,
                                                const float* __restrict__ als,
                                                const float* __restrict__ ald,
                                                const int* __restrict__ row_ptr,
                                                const int* __restrict__ csr_src,
                                                const float* __restrict__ bias,
                                                float* __restrict__ outp) {
  int gid = blockIdx.x * blockDim.x + threadIdx.x;
  int n = gid >> 6;
  int lane = threadIdx.x & 63;
  if (n >= NN) return;
  int head = lane >> 4;
  float ad = ald[n * 4 + head];
  int rs = row_ptr[n];
  int re = row_ptr[n + 1];
  float ax = 0.f, ay = 0.f, az = 0.f, aw = 0.f;
  float wsum = 0.f;
  const size_t loff = (size_t)lane * 4;

  int i = rs;
  // 4-wide batches: 4 independent als + h-row loads in flight per wave
  for (; i + 4 <= re; i += 4) {
    int s0 = csr_src[i], s1 = csr_src[i + 1], s2 = csr_src[i + 2], s3 = csr_src[i + 3];
    float al0 = als[s0 * 4 + head];
    float al1 = als[s1 * 4 + head];
    float al2 = als[s2 * 4 + head];
    float al3 = als[s3 * 4 + head];
    h4 v0 = *(const h4*)&h[(size_t)s0 * HCC + loff];
    h4 v1 = *(const h4*)&h[(size_t)s1 * HCC + loff];
    h4 v2 = *(const h4*)&h[(size_t)s2 * HCC + loff];
    h4 v3 = *(const h4*)&h[(size_t)s3 * HCC + loff];
    float w0 = edge_w(al0 + ad), w1 = edge_w(al1 + ad);
    float w2 = edge_w(al2 + ad), w3 = edge_w(al3 + ad);
    wsum += (w0 + w1) + (w2 + w3);
    ax = fmaf(w0, __half2float(v0.x), ax); ay = fmaf(w0, __half2float(v0.y), ay);
    az = fmaf(w0, __half2float(v0.z), az); aw = fmaf(w0, __half2float(v0.w), aw);
    ax = fmaf(w1, __half2float(v1.x), ax); ay = fmaf(w1, __half2float(v1.y), ay);
    az = fmaf(w1, __half2float(v1.z), az); aw = fmaf(w1, __half2float(v1.w), aw);
    ax = fmaf(w2, __half2float(v2.x), ax); ay = fmaf(w2, __half2float(v2.y), ay);
    az = fmaf(w2, __half2float(v2.z), az); aw = fmaf(w2, __half2float(v2.w), aw);
    ax = fmaf(w3, __half2float(v3.x), ax); ay = fmaf(w3, __half2float(v3.y), ay);
    az = fmaf(w3, __half2float(v3.z), az); aw = fmaf(w3, __half2float(v3.w), aw);
  }
  for (; i < re; ++i) {
    int s = csr_src[i];
    float w = edge_w(als[s * 4 + head] + ad);
    wsum += w;
    h4 hv = *(const h4*)&h[(size_t)s * HCC + loff];
    ax = fmaf(w, __half2float(hv.x), ax);
    ay = fmaf(w, __half2float(hv.y), ay);
    az = fmaf(w, __half2float(hv.z), az);
    aw = fmaf(w, __half2float(hv.w), aw);
  }
  if (SELFLOOP) {
    float w = edge_w(als[n * 4 + head] + ad);
    wsum += w;
    h4 hv = *(const h4*)&h[(size_t)n * HCC + loff];
    ax = fmaf(w, __half2float(hv.x), ax);
    ay = fmaf(w, __half2float(hv.y), ay);
    az = fmaf(w, __half2float(hv.z), az);
    aw = fmaf(w, __half2float(hv.w), aw);
  }
  float inv = 1.0f / (wsum + 1e-16f);
  if (CONCAT) {
    size_t base = (size_t)n * HCC + lane * 4;
    float4 bb = *(const float4*)&bias[lane * 4];
    float4 o;
    if (FIRST) {
      o.x = ax * inv + bb.x;
      o.y = ay * inv + bb.y;
      o.z = az * inv + bb.z;
      o.w = aw * inv + bb.w;
    } else {
      o = *(float4*)&outp[base];
      o.x += ax * inv + bb.x;
      o.y += ay * inv + bb.y;
      o.z += az * inv + bb.z;
      o.w += aw * inv + bb.w;
    }
    *(float4*)&outp[base] = o;
  } else {
    float vx = ax * inv, vy = ay * inv, vz = az * inv, vw = aw * inv;
    vx += __shfl_xor(vx, 16); vy += __shfl_xor(vy, 16);
    vz += __shfl_xor(vz, 16); vw += __shfl_xor(vw, 16);
    vx += __shfl_xor(vx, 32); vy += __shfl_xor(vy, 32);
    vz += __shfl_xor(vz, 32); vw += __shfl_xor(vw, 32);
    if (lane < 16) {
      size_t base = (size_t)n * OC + lane * 4;
      float4 bb = *(const float4*)&bias[lane * 4];
      float4 o;
      if (FIRST) {
        o.x = 0.25f * vx + bb.x;
        o.y = 0.25f * vy + bb.y;
        o.z = 0.25f * vz + bb.z;
        o.w = 0.25f * vw + bb.w;
      } else {
        o = *(float4*)&outp[base];
        o.x += 0.25f * vx + bb.x;
        o.y += 0.25f * vy + bb.y;
        o.z += 0.25f * vz + bb.z;
        o.w += 0.25f * vw + bb.w;
      }
      *(float4*)&outp[base] = o;
    }
  }
}

// ---------------- final: out = relu(out2) @ Wl + bl ----------------
__global__ __launch_bounds__(256) void k_final(const float* __restrict__ out2,
                                               const float* __restrict__ Wl,
                                               const float* __restrict__ bl,
                                               float* __restrict__ outp) {
  __shared__ float Ws[64 * 64];
  __shared__ float bs[64];
  int tid = threadIdx.x;
  for (int i = tid; i < 4096; i += 256) Ws[i] = Wl[i];
  if (tid < 64) bs[tid] = bl[tid];
  __syncthreads();
  int r = blockIdx.x * 4 + (tid >> 6);
  int c = tid & 63;
  if (r >= NN) return;
  const float* xr = &out2[(size_t)r * OC];
  float acc = bs[c];
#pragma unroll
  for (int k = 0; k < 64; ++k) {
    float xv = xr[k];
    xv = (xv > 0.f) ? xv : 0.f;
    acc = fmaf(xv, Ws[k * 64 + c], acc);
  }
  outp[(size_t)r * OC + c] = acc;
}

extern "C" void kernel_launch(void* const* d_in, const int* in_sizes, int n_in,
                              void* d_out, int out_size, void* d_ws, size_t ws_size,
                              hipStream_t stream) {
  const float* x   = (const float*)d_in[0];
  const int* e_b   = (const int*)d_in[1];
  const int* e_sp  = (const int*)d_in[2];
  const int* e_si  = (const int*)d_in[3];
  const float* W1  = (const float*)d_in[4];
  const float* a1s = (const float*)d_in[5];
  const float* a1d = (const float*)d_in[6];
  const float* b1  = (const float*)d_in[7];
  const float* W2  = (const float*)d_in[8];
  const float* a2s = (const float*)d_in[9];
  const float* a2d = (const float*)d_in[10];
  const float* b2  = (const float*)d_in[11];
  const float* Wl  = (const float*)d_in[12];
  const float* bl  = (const float*)d_in[13];
  float* out = (float*)d_out;

  char* ws = (char*)d_ws;
  size_t off = 0;
  auto alloc = [&](size_t b) {
    char* p = ws + off;
    off += (b + 255) & ~(size_t)255;
    return p;
  };
  __half* h   = (__half*)alloc((size_t)NN * HCC * 2);
  float* out1 = (float*)alloc((size_t)NN * HCC * 4);
  float* out2 = (float*)alloc((size_t)NN * OC * 4);
  float* als  = (float*)alloc((size_t)NN * 4 * 4);
  float* ald  = (float*)alloc((size_t)NN * 4 * 4);
  int* deg3   = (int*)alloc((size_t)NT3 * 4);
  int* cursor3= (int*)alloc((size_t)NT3 * 4);
  int* rpA    = (int*)alloc((size_t)3 * (NN + 1) * 4);
  int* bsum   = (int*)alloc(256 * 4);
  int* boffs  = (int*)alloc(256 * 4);
  short* Wc1  = (short*)alloc((size_t)3 * 4 * FIN * 128 * 2);
  short* Wc2  = (short*)alloc((size_t)3 * 4 * HCC * 128 * 2);
  int* cs[3];
  for (int r = 0; r < 3; ++r) cs[r] = (int*)alloc((size_t)NE * 4);

  const int* edges[3] = {e_b, e_sp, e_si};

  // weight pre-split (tiny)
  k_prep<FIN><<<(3 * FIN * 256 + 255) / 256, 256, 0, stream>>>(W1, Wc1);
  k_prep<HCC><<<(3 * HCC * 256 + 255) / 256, 256, 0, stream>>>(W2, Wc2);

  // CSR build: 3 relations fused through one scan
  hipMemsetAsync(deg3, 0, (size_t)NT3 * 4, stream);
  for (int r = 0; r < 3; ++r)
    k_hist<<<1024, 256, 0, stream>>>(edges[r] + NE, deg3 + r * NN, NE);
  const int NB = (NT3 + 1023) / 1024;  // 147
  k_bsum<<<NB, 1024, 0, stream>>>(deg3, bsum);
  k_scan2<<<1, 256, 0, stream>>>(bsum, boffs, NB);
  k_rowptr<<<NB, 1024, 0, stream>>>(deg3, boffs, rpA, cursor3);
  for (int r = 0; r < 3; ++r)
    k_scatter<<<1024, 256, 0, stream>>>(edges[r], edges[r] + NE, cursor3 + r * NN, cs[r], NE);

  const int gblocks = (NN + 63) / 64;  // 782
  const int ablocks = (NN * 64) / 256; // 12500

  // layer 1 (concat)
  for (int r = 0; r < 3; ++r) {
    k_mgemm<FIN, false><<<gblocks, 256, 0, stream>>>(
        x, Wc1 + (size_t)r * 4 * FIN * 128,
        a1s + r * HCC, a1d + r * HCC, h, als, ald, NN);
    if (r == 0)
      k_gather<true, false, true><<<ablocks, 256, 0, stream>>>(h, als, ald, rpA + r * (NN + 1), cs[r], b1 + r * HCC, out1);
    else
      k_gather<true, true, false><<<ablocks, 256, 0, stream>>>(h, als, ald, rpA + r * (NN + 1), cs[r], b1 + r * HCC, out1);
  }
  // layer 2 (mean over heads); relu fused into GEMM A-conversion
  for (int r = 0; r < 3; ++r) {
    k_mgemm<HCC, true><<<gblocks, 256, 0, stream>>>(
        out1, Wc2 + (size_t)r * 4 * HCC * 128,
        a2s + r * HCC, a2d + r * HCC, h, als, ald, NN);
    if (r == 0)
      k_gather<false, false, true><<<ablocks, 256, 0, stream>>>(h, als, ald, rpA + r * (NN + 1), cs[r], b2 + r * OC, out2);
    else
      k_gather<false, true, false><<<ablocks, 256, 0, stream>>>(h, als, ald, rpA + r * (NN + 1), cs[r], b2 + r * OC, out2);
  }
  // final linear (relu on out2 fused)
  k_final<<<(NN + 3) / 4, 256, 0, stream>>>(out2, Wl, bl, out);
}

// Round 6
// 907.066 us; speedup vs baseline: 2.1200x; 1.1038x over previous
//
#include <hip/hip_runtime.h>
#include <hip/hip_bf16.h>
#include <hip/hip_fp16.h>

#define NN 50000
#define NE 800000
#define FIN 128
#define HCC 256   // HEADS*HID
#define OC 64
#define NSL 0.2f
#define NT3 (3 * NN)

typedef __attribute__((ext_vector_type(8))) short sh8;
typedef __attribute__((ext_vector_type(8))) unsigned short u16x8;
typedef __attribute__((ext_vector_type(16))) float f32x16;

struct __attribute__((aligned(8))) h4 { __half x, y, z, w; };

__device__ __forceinline__ unsigned short bf_rne(float f) {
  unsigned u = __float_as_uint(f);
  u += 0x7FFF + ((u >> 16) & 1);
  return (unsigned short)(u >> 16);
}

__device__ __forceinline__ float hbits2f(unsigned short u) {
  __half_raw hr; hr.x = u;
  return __half2float((__half)hr);
}

__device__ __forceinline__ float edge_w(float lg) {
  lg = (lg > 0.f) ? lg : NSL * lg;
  return __expf(lg);
}

// -------- weight pre-split into chunked-coalesced layout --------
// W:[3][KK][256] fp32 -> out:[3][cb(2)][hl(2)][KK/8][c(128)][8] bf16
template<int KK>
__global__ __launch_bounds__(256) void k_prep(const float* __restrict__ W,
                                              short* __restrict__ out) {
  int i = blockIdx.x * 256 + threadIdx.x;
  if (i >= 3 * KK * 256) return;
  int r = i / (KK * 256);
  int rem = i - r * KK * 256;
  int k = rem >> 8;
  int n = rem & 255;
  float f = W[i];
  unsigned short hb = bf_rne(f);
  float hf = __uint_as_float(((unsigned)hb) << 16);
  unsigned short lb = bf_rne(f - hf);
  int cb = n >> 7, c = n & 127, ks8 = k >> 3, kj = k & 7;
  size_t base = (size_t)r * 4 * KK * 128;
  size_t oh = base + ((size_t)((cb * 2 + 0) * (KK / 8) + ks8) * 128 + c) * 8 + kj;
  size_t ol = base + ((size_t)((cb * 2 + 1) * (KK / 8) + ks8) * 128 + c) * 8 + kj;
  out[oh] = (short)hb;
  out[ol] = (short)lb;
}

// ---------------- CSR build ----------------
__global__ void k_hist(const int* __restrict__ dst, int* __restrict__ deg, int n) {
  int i = blockIdx.x * blockDim.x + threadIdx.x;
  int st = gridDim.x * blockDim.x;
  for (; i < n; i += st) atomicAdd(&deg[dst[i]], 1);
}

__global__ __launch_bounds__(1024) void k_bsum(const int* __restrict__ deg3,
                                               int* __restrict__ bsum) {
  __shared__ int s[1024];
  int t = threadIdx.x;
  int i = blockIdx.x * 1024 + t;
  s[t] = (i < NT3) ? deg3[i] : 0;
  __syncthreads();
  for (int off = 512; off > 0; off >>= 1) {
    if (t < off) s[t] += s[t + off];
    __syncthreads();
  }
  if (t == 0) bsum[blockIdx.x] = s[0];
}

__global__ __launch_bounds__(256) void k_scan2(const int* __restrict__ bsum,
                                               int* __restrict__ boffs, int nb) {
  __shared__ int s[256];
  int t = threadIdx.x;
  int v = (t < nb) ? bsum[t] : 0;
  s[t] = v;
  __syncthreads();
  for (int off = 1; off < 256; off <<= 1) {
    int x = (t >= off) ? s[t - off] : 0;
    __syncthreads();
    s[t] += x;
    __syncthreads();
  }
  if (t < nb) boffs[t] = s[t] - v;  // exclusive
}

__global__ __launch_bounds__(1024) void k_rowptr(const int* __restrict__ deg3,
                                                 const int* __restrict__ boffs,
                                                 int* __restrict__ rpA,
                                                 int* __restrict__ cursor3) {
  __shared__ int s[1024];
  int t = threadIdx.x;
  int i = blockIdx.x * 1024 + t;
  int d = (i < NT3) ? deg3[i] : 0;
  s[t] = d;
  __syncthreads();
  for (int off = 1; off < 1024; off <<= 1) {
    int x = (t >= off) ? s[t - off] : 0;
    __syncthreads();
    s[t] += x;
    __syncthreads();
  }
  if (i < NT3) {
    int excl = boffs[blockIdx.x] + s[t] - d;
    int r = (i < NN) ? 0 : ((i < 2 * NN) ? 1 : 2);
    int n = i - r * NN;
    int val = excl - r * NE;
    rpA[r * (NN + 1) + n] = val;
    cursor3[i] = val;
  }
  if (blockIdx.x == 0 && t < 3) rpA[t * (NN + 1) + NN] = NE;
}

__global__ void k_scatter(const int* __restrict__ srcv, const int* __restrict__ dstv,
                          int* __restrict__ cursor, int* __restrict__ csr_src, int n) {
  int i = blockIdx.x * blockDim.x + threadIdx.x;
  int st = gridDim.x * blockDim.x;
  for (; i < n; i += st) {
    int pos = atomicAdd(&cursor[dstv[i]], 1);
    csr_src[pos] = srcv[i];
  }
}

// -------- split-bf16 MFMA GEMM (32x32x16), all 3 relations in one launch --------
// blockIdx.y = relation. A: fp32 (layer1) or fp16 post-relu (layer2).
template<int KK, bool AF32>
__global__ __launch_bounds__(256) void k_mgemm(const void* __restrict__ Av,
                                               const short* __restrict__ BcAll,
                                               const float* __restrict__ asfAll,
                                               const float* __restrict__ adfAll,
                                               __half* __restrict__ houtAll,
                                               float* __restrict__ alsAll,
                                               float* __restrict__ aldAll, int M) {
  const int rel = blockIdx.y;
  const short* Bc = BcAll + (size_t)rel * 4 * KK * 128;
  const float* asf = asfAll + rel * HCC;
  const float* adf = adfAll + rel * HCC;
  __half* hout = houtAll + (size_t)rel * NN * HCC;
  float* als = alsAll + (size_t)rel * NN * 4;
  float* ald = aldAll + (size_t)rel * NN * 4;

  const int tid = threadIdx.x;
  const int lane = tid & 63;
  const int w = tid >> 6;
  const int l31 = lane & 31;
  const int lg = lane >> 5;
  const int wrow = blockIdx.x * 64 + (w & 1) * 32;
  const int ch = w >> 1;

  f32x16 acc[4];
#pragma unroll
  for (int t = 0; t < 4; ++t) acc[t] = (f32x16)(0.f);

  const int r = wrow + l31;
  const bool aok = r < M;
  const float* apf = (const float*)Av + (size_t)r * KK;
  const __half* aph = (const __half*)Av + (size_t)r * KK;
  const short* bh = Bc + (size_t)(ch * 2 + 0) * KK * 128 + l31 * 8;
  const short* bl = Bc + (size_t)(ch * 2 + 1) * KK * 128 + l31 * 8;

#pragma unroll 2
  for (int kst = 0; kst < KK / 16; ++kst) {
    const int k0 = kst * 16 + lg * 8;
    float fa[8];
    if (AF32) {
      float4 x0 = make_float4(0.f, 0.f, 0.f, 0.f), x1 = x0;
      if (aok) {
        x0 = *(const float4*)(apf + k0);
        x1 = *(const float4*)(apf + k0 + 4);
      }
      fa[0] = x0.x; fa[1] = x0.y; fa[2] = x0.z; fa[3] = x0.w;
      fa[4] = x1.x; fa[5] = x1.y; fa[6] = x1.z; fa[7] = x1.w;
    } else {
      u16x8 hv = {0, 0, 0, 0, 0, 0, 0, 0};
      if (aok) hv = *(const u16x8*)(aph + k0);
#pragma unroll
      for (int j = 0; j < 8; ++j) fa[j] = hbits2f(hv[j]);
    }
    const int ks8 = kst * 2 + lg;
    const short* bhp = bh + (size_t)ks8 * 1024;
    const short* blp = bl + (size_t)ks8 * 1024;
    sh8 bhf[4], blf[4];
#pragma unroll
    for (int t = 0; t < 4; ++t) {
      bhf[t] = *(const sh8*)(bhp + t * 256);
      blf[t] = *(const sh8*)(blp + t * 256);
    }
    sh8 ahi, alo;
#pragma unroll
    for (int j = 0; j < 8; ++j) {
      float f = fa[j];
      unsigned short hb = bf_rne(f);
      float hf = __uint_as_float(((unsigned)hb) << 16);
      unsigned short lb = bf_rne(f - hf);
      ahi[j] = (short)hb;
      alo[j] = (short)lb;
    }
#pragma unroll
    for (int t = 0; t < 4; ++t) {
      acc[t] = __builtin_amdgcn_mfma_f32_32x32x16_bf16(ahi, bhf[t], acc[t], 0, 0, 0);
      acc[t] = __builtin_amdgcn_mfma_f32_32x32x16_bf16(alo, bhf[t], acc[t], 0, 0, 0);
      acc[t] = __builtin_amdgcn_mfma_f32_32x32x16_bf16(ahi, blf[t], acc[t], 0, 0, 0);
    }
  }

  // epilogue: h (fp16) store + fused alpha (2 heads per col-half)
  float asr[4], adr[4];
#pragma unroll
  for (int t = 0; t < 4; ++t) {
    int col = ch * 128 + t * 32 + l31;
    asr[t] = asf[col];
    adr[t] = adf[col];
  }
#pragma unroll
  for (int v = 0; v < 16; ++v) {
    const int rl = (v & 3) + 8 * (v >> 2) + 4 * lg;
    const int row = wrow + rl;
    const bool rok = row < M;
    float s0 = 0.f, s1 = 0.f, d0 = 0.f, d1 = 0.f;
    __half* hp = hout + (size_t)row * 256 + ch * 128 + l31;
#pragma unroll
    for (int t = 0; t < 4; ++t) {
      float dv = acc[t][v];
      if (rok) hp[t * 32] = __float2half(dv);
      if (t < 2) { s0 += dv * asr[t]; d0 += dv * adr[t]; }
      else       { s1 += dv * asr[t]; d1 += dv * adr[t]; }
    }
#pragma unroll
    for (int m = 1; m < 32; m <<= 1) {
      s0 += __shfl_xor(s0, m);
      s1 += __shfl_xor(s1, m);
      d0 += __shfl_xor(d0, m);
      d1 += __shfl_xor(d1, m);
    }
    if (rok && l31 == 0) {
      *(float2*)(als + (size_t)row * 4 + ch * 2) = make_float2(s0, s1);
      *(float2*)(ald + (size_t)row * 4 + ch * 2) = make_float2(d0, d1);
    }
  }
}

// ---------------- fused 3-relation gather ----------------
template<bool SL>
__device__ __forceinline__ void gat_rel(int n, int head, size_t loff,
                                        const __half* __restrict__ h,
                                        const float* __restrict__ als,
                                        const float* __restrict__ ald,
                                        const int* __restrict__ rp,
                                        const int* __restrict__ cs,
                                        float& ox, float& oy, float& oz, float& ow) {
  float ad = ald[n * 4 + head];
  int rs = rp[n], re = rp[n + 1];
  float ax = 0.f, ay = 0.f, az = 0.f, aw = 0.f, wsum = 0.f;
  int i = rs;
  for (; i + 4 <= re; i += 4) {
    int s0 = cs[i], s1 = cs[i + 1], s2 = cs[i + 2], s3 = cs[i + 3];
    float al0 = als[s0 * 4 + head];
    float al1 = als[s1 * 4 + head];
    float al2 = als[s2 * 4 + head];
    float al3 = als[s3 * 4 + head];
    h4 v0 = *(const h4*)&h[(size_t)s0 * HCC + loff];
    h4 v1 = *(const h4*)&h[(size_t)s1 * HCC + loff];
    h4 v2 = *(const h4*)&h[(size_t)s2 * HCC + loff];
    h4 v3 = *(const h4*)&h[(size_t)s3 * HCC + loff];
    float w0 = edge_w(al0 + ad), w1 = edge_w(al1 + ad);
    float w2 = edge_w(al2 + ad), w3 = edge_w(al3 + ad);
    wsum += (w0 + w1) + (w2 + w3);
    ax = fmaf(w0, __half2float(v0.x), ax); ay = fmaf(w0, __half2float(v0.y), ay);
    az = fmaf(w0, __half2float(v0.z), az); aw = fmaf(w0, __half2float(v0.w), aw);
    ax = fmaf(w1, __half2float(v1.x), ax); ay = fmaf(w1, __half2float(v1.y), ay);
    az = fmaf(w1, __half2float(v1.z), az); aw = fmaf(w1, __half2float(v1.w), aw);
    ax = fmaf(w2, __half2float(v2.x), ax); ay = fmaf(w2, __half2float(v2.y), ay);
    az = fmaf(w2, __half2float(v2.z), az); aw = fmaf(w2, __half2float(v2.w), aw);
    ax = fmaf(w3, __half2float(v3.x), ax); ay = fmaf(w3, __half2float(v3.y), ay);
    az = fmaf(w3, __half2float(v3.z), az); aw = fmaf(w3, __half2float(v3.w), aw);
  }
  for (; i < re; ++i) {
    int s = cs[i];
    float w = edge_w(als[s * 4 + head] + ad);
    wsum += w;
    h4 hv = *(const h4*)&h[(size_t)s * HCC + loff];
    ax = fmaf(w, __half2float(hv.x), ax);
    ay = fmaf(w, __half2float(hv.y), ay);
    az = fmaf(w, __half2float(hv.z), az);
    aw = fmaf(w, __half2float(hv.w), aw);
  }
  if (SL) {
    float w = edge_w(als[n * 4 + head] + ad);
    wsum += w;
    h4 hv = *(const h4*)&h[(size_t)n * HCC + loff];
    ax = fmaf(w, __half2float(hv.x), ax);
    ay = fmaf(w, __half2float(hv.y), ay);
    az = fmaf(w, __half2float(hv.z), az);
    aw = fmaf(w, __half2float(hv.w), aw);
  }
  float inv = 1.0f / (wsum + 1e-16f);
  ox = fmaf(ax, inv, ox);
  oy = fmaf(ay, inv, oy);
  oz = fmaf(az, inv, oz);
  ow = fmaf(aw, inv, ow);
}

// CONCAT: out1h[n,256] = fp16 relu(sum_r gat + sum_r bias)
// !CONCAT: out2[n,64] = fp32 head-mean + sum_r bias
template<bool CONCAT>
__global__ __launch_bounds__(256) void k_gather3(const __half* __restrict__ h3,
                                                 const float* __restrict__ als3,
                                                 const float* __restrict__ ald3,
                                                 const int* __restrict__ rpA,
                                                 const int* __restrict__ cs0,
                                                 const int* __restrict__ cs1,
                                                 const int* __restrict__ cs2,
                                                 const float* __restrict__ bias,
                                                 __half* __restrict__ o16,
                                                 float* __restrict__ o32) {
  int gid = blockIdx.x * blockDim.x + threadIdx.x;
  int n = gid >> 6;
  int lane = threadIdx.x & 63;
  if (n >= NN) return;
  int head = lane >> 4;
  size_t loff = (size_t)lane * 4;
  const size_t HS = (size_t)NN * HCC;
  const size_t AS = (size_t)NN * 4;
  float ox = 0.f, oy = 0.f, oz = 0.f, ow = 0.f;
  gat_rel<false>(n, head, loff, h3,          als3,          ald3,          rpA,               cs0, ox, oy, oz, ow);
  gat_rel<true >(n, head, loff, h3 + HS,     als3 + AS,     ald3 + AS,     rpA + (NN + 1),    cs1, ox, oy, oz, ow);
  gat_rel<true >(n, head, loff, h3 + 2 * HS, als3 + 2 * AS, ald3 + 2 * AS, rpA + 2 * (NN + 1), cs2, ox, oy, oz, ow);
  if (CONCAT) {
    float4 b0 = *(const float4*)&bias[lane * 4];
    float4 b1 = *(const float4*)&bias[HCC + lane * 4];
    float4 b2 = *(const float4*)&bias[2 * HCC + lane * 4];
    h4 o;
    o.x = __float2half(fmaxf(ox + b0.x + b1.x + b2.x, 0.f));
    o.y = __float2half(fmaxf(oy + b0.y + b1.y + b2.y, 0.f));
    o.z = __float2half(fmaxf(oz + b0.z + b1.z + b2.z, 0.f));
    o.w = __float2half(fmaxf(ow + b0.w + b1.w + b2.w, 0.f));
    *(h4*)&o16[(size_t)n * HCC + loff] = o;
  } else {
    ox += __shfl_xor(ox, 16); oy += __shfl_xor(oy, 16);
    oz += __shfl_xor(oz, 16); ow += __shfl_xor(ow, 16);
    ox += __shfl_xor(ox, 32); oy += __shfl_xor(oy, 32);
    oz += __shfl_xor(oz, 32); ow += __shfl_xor(ow, 32);
    if (lane < 16) {
      float4 b0 = *(const float4*)&bias[lane * 4];
      float4 b1 = *(const float4*)&bias[OC + lane * 4];
      float4 b2 = *(const float4*)&bias[2 * OC + lane * 4];
      float4 o;
      o.x = 0.25f * ox + b0.x + b1.x + b2.x;
      o.y = 0.25f * oy + b0.y + b1.y + b2.y;
      o.z = 0.25f * oz + b0.z + b1.z + b2.z;
      o.w = 0.25f * ow + b0.w + b1.w + b2.w;
      *(float4*)&o32[(size_t)n * OC + lane * 4] = o;
    }
  }
}

// ---------------- final: out = relu(out2) @ Wl + bl ----------------
__global__ __launch_bounds__(256) void k_final(const float* __restrict__ out2,
                                               const float* __restrict__ Wl,
                                               const float* __restrict__ bl,
                                               float* __restrict__ outp) {
  __shared__ float Ws[64 * 64];
  __shared__ float bs[64];
  int tid = threadIdx.x;
  for (int i = tid; i < 4096; i += 256) Ws[i] = Wl[i];
  if (tid < 64) bs[tid] = bl[tid];
  __syncthreads();
  int r = blockIdx.x * 4 + (tid >> 6);
  int c = tid & 63;
  if (r >= NN) return;
  const float* xr = &out2[(size_t)r * OC];
  float acc = bs[c];
#pragma unroll
  for (int k = 0; k < 64; ++k) {
    float xv = xr[k];
    xv = (xv > 0.f) ? xv : 0.f;
    acc = fmaf(xv, Ws[k * 64 + c], acc);
  }
  outp[(size_t)r * OC + c] = acc;
}

extern "C" void kernel_launch(void* const* d_in, const int* in_sizes, int n_in,
                              void* d_out, int out_size, void* d_ws, size_t ws_size,
                              hipStream_t stream) {
  const float* x   = (const float*)d_in[0];
  const int* e_b   = (const int*)d_in[1];
  const int* e_sp  = (const int*)d_in[2];
  const int* e_si  = (const int*)d_in[3];
  const float* W1  = (const float*)d_in[4];
  const float* a1s = (const float*)d_in[5];
  const float* a1d = (const float*)d_in[6];
  const float* b1  = (const float*)d_in[7];
  const float* W2  = (const float*)d_in[8];
  const float* a2s = (const float*)d_in[9];
  const float* a2d = (const float*)d_in[10];
  const float* b2  = (const float*)d_in[11];
  const float* Wl  = (const float*)d_in[12];
  const float* bl  = (const float*)d_in[13];
  float* out = (float*)d_out;

  char* ws = (char*)d_ws;
  size_t off = 0;
  auto alloc = [&](size_t b) {
    char* p = ws + off;
    off += (b + 255) & ~(size_t)255;
    return p;
  };
  __half* h3   = (__half*)alloc((size_t)3 * NN * HCC * 2);  // 76.8 MB
  __half* out1h = (__half*)alloc((size_t)NN * HCC * 2);     // 25.6 MB (also reused as out2 fp32)
  float* out2 = (float*)out1h;                               // alias: out1h dead when out2 written
  float* als3 = (float*)alloc((size_t)3 * NN * 4 * 4);
  float* ald3 = (float*)alloc((size_t)3 * NN * 4 * 4);
  int* deg3   = (int*)alloc((size_t)NT3 * 4);
  int* cursor3= (int*)alloc((size_t)NT3 * 4);
  int* rpA    = (int*)alloc((size_t)3 * (NN + 1) * 4);
  int* bsum   = (int*)alloc(256 * 4);
  int* boffs  = (int*)alloc(256 * 4);
  short* Wc1  = (short*)alloc((size_t)3 * 4 * FIN * 128 * 2);
  short* Wc2  = (short*)alloc((size_t)3 * 4 * HCC * 128 * 2);
  int* cs[3];
  for (int r = 0; r < 3; ++r) cs[r] = (int*)alloc((size_t)NE * 4);

  const int* edges[3] = {e_b, e_sp, e_si};

  // weight pre-split (tiny)
  k_prep<FIN><<<(3 * FIN * 256 + 255) / 256, 256, 0, stream>>>(W1, Wc1);
  k_prep<HCC><<<(3 * HCC * 256 + 255) / 256, 256, 0, stream>>>(W2, Wc2);

  // CSR build: 3 relations fused through one scan
  hipMemsetAsync(deg3, 0, (size_t)NT3 * 4, stream);
  for (int r = 0; r < 3; ++r)
    k_hist<<<1024, 256, 0, stream>>>(edges[r] + NE, deg3 + r * NN, NE);
  const int NB = (NT3 + 1023) / 1024;  // 147
  k_bsum<<<NB, 1024, 0, stream>>>(deg3, bsum);
  k_scan2<<<1, 256, 0, stream>>>(bsum, boffs, NB);
  k_rowptr<<<NB, 1024, 0, stream>>>(deg3, boffs, rpA, cursor3);
  for (int r = 0; r < 3; ++r)
    k_scatter<<<1024, 256, 0, stream>>>(edges[r], edges[r] + NE, cursor3 + r * NN, cs[r], NE);

  const int gblocks = (NN + 63) / 64;  // 782
  const int ablocks = (NN * 64) / 256; // 12500

  // layer 1: 3-relation GEMM (one launch) + fused 3-relation gather (concat, relu, fp16)
  k_mgemm<FIN, true><<<dim3(gblocks, 3), 256, 0, stream>>>(
      x, Wc1, a1s, a1d, h3, als3, ald3, NN);
  k_gather3<true><<<ablocks, 256, 0, stream>>>(
      h3, als3, ald3, rpA, cs[0], cs[1], cs[2], b1, out1h, nullptr);

  // layer 2: fp16 A input (pre-relu'd), head-mean gather
  k_mgemm<HCC, false><<<dim3(gblocks, 3), 256, 0, stream>>>(
      out1h, Wc2, a2s, a2d, h3, als3, ald3, NN);
  k_gather3<false><<<ablocks, 256, 0, stream>>>(
      h3, als3, ald3, rpA, cs[0], cs[1], cs[2], b2, nullptr, out2);

  // final linear (relu on out2 fused)
  k_final<<<(NN + 3) / 4, 256, 0, stream>>>(out2, Wl, bl, out);
}